// Round 1
// baseline (753.925 us; speedup 1.0000x reference)
//
#include <hip/hip_runtime.h>
#include <math.h>

#define NBATCH 16
#define NPTS   1024
#define S1     512
#define S2     128
#define MAXN   64
#define N1     (NBATCH*S1)   /* 8192  */
#define N2     (NBATCH*S2)   /* 2048  */

// ---------------- workspace layout (float offsets) ----------------
#define POS1_OFF  0           /* 8192*3  = 24576  */
#define POS2_OFF  24576       /* 2048*3  = 6144   */
#define X1_OFF    30720       /* 8192*128 = 1048576 */
#define X2_OFF    1079296     /* 2048*256 = 524288  */
#define GPART_OFF 1603584     /* 256*1024 = 262144  */
#define G_OFF     1865728     /* 16*1024  = 16384   */
#define H1_OFF    1882112     /* 16*512   = 8192    */
#define H2_OFF    1890304     /* 16*256   = 4096    */

__device__ __forceinline__ float wave_max64(float v) {
#pragma unroll
  for (int off = 1; off < 64; off <<= 1)
    v = fmaxf(v, __shfl_xor(v, off, 64));
  return v;
}

// ---------------- K0: gather pos1 = pos[idx1], pos2 = pos[idx1[idx2]] ----------------
__global__ __launch_bounds__(256) void k_gather(const float* __restrict__ pos,
                                                const int* __restrict__ idx1,
                                                const int* __restrict__ idx2,
                                                float* __restrict__ pos1,
                                                float* __restrict__ pos2) {
  int i = blockIdx.x * 256 + threadIdx.x;
  if (i < N1) {
    int s = idx1[i];
    pos1[i*3+0] = pos[s*3+0];
    pos1[i*3+1] = pos[s*3+1];
    pos1[i*3+2] = pos[s*3+2];
  } else if (i < N1 + N2) {
    int j = i - N1;
    int s = idx1[idx2[j]];
    pos2[j*3+0] = pos[s*3+0];
    pos2[j*3+1] = pos[s*3+1];
    pos2[j*3+2] = pos[s*3+2];
  }
}

// ---------------- K1: conv1  (feat=rel(3) -> 64 -> 64 -> 128, segmax over 64 edges) ----
// grid 8192 (one block per dst segment), block 256 (4 waves; lane = edge, wave = ch slice)
__global__ __launch_bounds__(256) void k_conv1(
    const float* __restrict__ pos, const float* __restrict__ pos1,
    const int* __restrict__ esrc,
    const float* __restrict__ w1a, const float* __restrict__ b1a,
    const float* __restrict__ w1b, const float* __restrict__ b1b,
    const float* __restrict__ w1c, const float* __restrict__ b1c,
    float* __restrict__ x1) {
  __shared__ float srel[MAXN][4];
  __shared__ float sh[MAXN * 65];
  __shared__ float sh2[MAXN * 65];
  __shared__ int   svalid[MAXN];

  int seg  = blockIdx.x;
  int tid  = threadIdx.x;
  int lane = tid & 63;
  int ww   = __builtin_amdgcn_readfirstlane(tid >> 6);  // 0..3

  if (tid < MAXN) {
    int e = seg * MAXN + tid;
    int s = esrc[e];
    int valid = (tid == 0) || (s > esrc[e - 1]);
    svalid[tid] = valid;
    srel[tid][0] = pos[s*3+0] - pos1[seg*3+0];
    srel[tid][1] = pos[s*3+1] - pos1[seg*3+1];
    srel[tid][2] = pos[s*3+2] - pos1[seg*3+2];
  }
  __syncthreads();

  // layer A: 3 -> 64 (wave ww handles ch [ww*16, ww*16+16))
  {
    float r0 = srel[lane][0], r1 = srel[lane][1], r2 = srel[lane][2];
    const float* wp = w1a + ww * 16;
#pragma unroll
    for (int j = 0; j < 16; j++) {
      float a = b1a[ww*16 + j] + r0 * wp[j] + r1 * wp[64 + j] + r2 * wp[128 + j];
      sh[lane * 65 + ww * 16 + j] = fmaxf(a, 0.f);
    }
  }
  __syncthreads();

  // layer B: 64 -> 64
  {
    float acc[16];
#pragma unroll
    for (int j = 0; j < 16; j++) acc[j] = b1b[ww*16 + j];
    for (int k = 0; k < 64; k++) {
      float a = sh[lane * 65 + k];
      const float* wr = w1b + k * 64 + ww * 16;
#pragma unroll
      for (int j = 0; j < 16; j++) acc[j] += a * wr[j];
    }
#pragma unroll
    for (int j = 0; j < 16; j++) sh2[lane * 65 + ww * 16 + j] = fmaxf(acc[j], 0.f);
  }
  __syncthreads();

  // layer C: 64 -> 128 (wave ww handles ch [ww*32, ww*32+32)), then segment max + relu
  {
    float acc[32];
#pragma unroll
    for (int j = 0; j < 32; j++) acc[j] = b1c[ww*32 + j];
    for (int k = 0; k < 64; k++) {
      float a = sh2[lane * 65 + k];
      const float* wr = w1c + k * 128 + ww * 32;
#pragma unroll
      for (int j = 0; j < 32; j++) acc[j] += a * wr[j];
    }
    bool val = svalid[lane] != 0;
    float myv = 0.f;
#pragma unroll
    for (int j = 0; j < 32; j++) {
      float v = val ? acc[j] : -INFINITY;
      v = wave_max64(v);
      if (lane == j) myv = v;
    }
    if (lane < 32) x1[seg * 128 + ww * 32 + lane] = fmaxf(myv, 0.f);
  }
}

// ---------------- K2: conv2 (feat=[x1(128),rel(3)] -> 128 -> 128 -> 256, segmax) -------
// grid 2048, block 256
__global__ __launch_bounds__(256) void k_conv2(
    const float* __restrict__ pos1, const float* __restrict__ pos2,
    const int* __restrict__ esrc, const float* __restrict__ x1,
    const float* __restrict__ w2a, const float* __restrict__ b2a,
    const float* __restrict__ w2b, const float* __restrict__ b2b,
    const float* __restrict__ w2c, const float* __restrict__ b2c,
    float* __restrict__ x2) {
  __shared__ float sfeat[MAXN * 133];
  __shared__ float sh[MAXN * 133];
  __shared__ int   svalid[MAXN];

  int seg  = blockIdx.x;
  int tid  = threadIdx.x;
  int lane = tid & 63;
  int ww   = __builtin_amdgcn_readfirstlane(tid >> 6);

  // stage feat = [x1[src], rel]
  {
    int e = tid >> 2, part = tid & 3;
    int s = esrc[seg * MAXN + e];
    const float4* xr = (const float4*)(x1 + s * 128 + part * 32);
    float* dp = sfeat + e * 133 + part * 32;
#pragma unroll
    for (int i = 0; i < 8; i++) {
      float4 v = xr[i];
      dp[i*4+0] = v.x; dp[i*4+1] = v.y; dp[i*4+2] = v.z; dp[i*4+3] = v.w;
    }
  }
  if (tid < MAXN) {
    int e = seg * MAXN + tid;
    int s = esrc[e];
    svalid[tid] = (tid == 0) || (s > esrc[e - 1]);
#pragma unroll
    for (int c = 0; c < 3; c++)
      sfeat[tid * 133 + 128 + c] = pos1[s*3+c] - pos2[seg*3+c];
  }
  __syncthreads();

  // layer A: 131 -> 128 (wave ww: ch [ww*32, ww*32+32))
  {
    float acc[32];
#pragma unroll
    for (int j = 0; j < 32; j++) acc[j] = b2a[ww*32 + j];
    for (int k = 0; k < 131; k++) {
      float a = sfeat[lane * 133 + k];
      const float* wr = w2a + k * 128 + ww * 32;
#pragma unroll
      for (int j = 0; j < 32; j++) acc[j] += a * wr[j];
    }
#pragma unroll
    for (int j = 0; j < 32; j++) sh[lane * 133 + ww * 32 + j] = fmaxf(acc[j], 0.f);
  }
  __syncthreads();

  // layer B: 128 -> 128
  {
    float acc[32];
#pragma unroll
    for (int j = 0; j < 32; j++) acc[j] = b2b[ww*32 + j];
    for (int k = 0; k < 128; k++) {
      float a = sh[lane * 133 + k];
      const float* wr = w2b + k * 128 + ww * 32;
#pragma unroll
      for (int j = 0; j < 32; j++) acc[j] += a * wr[j];
    }
    __syncthreads();  // sfeat being overwritten below; all reads of sfeat layerA done
#pragma unroll
    for (int j = 0; j < 32; j++) sfeat[lane * 133 + ww * 32 + j] = fmaxf(acc[j], 0.f);
  }
  __syncthreads();

  // layer C: 128 -> 256 (wave ww: ch [ww*64, ww*64+64)), segment max + relu
  {
    float acc[64];
#pragma unroll
    for (int j = 0; j < 64; j++) acc[j] = b2c[ww*64 + j];
    for (int k = 0; k < 128; k++) {
      float a = sfeat[lane * 133 + k];
      const float* wr = w2c + k * 256 + ww * 64;
#pragma unroll
      for (int j = 0; j < 64; j++) acc[j] += a * wr[j];
    }
    bool val = svalid[lane] != 0;
    float myv = 0.f;
#pragma unroll
    for (int j = 0; j < 64; j++) {
      float v = val ? acc[j] : -INFINITY;
      v = wave_max64(v);
      if (lane == j) myv = v;
    }
    x2[seg * 256 + ww * 64 + lane] = fmaxf(myv, 0.f);
  }
}

// ---------------- K3: g-MLP (259 -> 256 -> 512 -> 1024) + partial max over 8 points ----
// grid 256 (8 points each, all within one batch), block 256
__global__ __launch_bounds__(256) void k_gmlp(
    const float* __restrict__ x2, const float* __restrict__ pos2,
    const float* __restrict__ g1w, const float* __restrict__ g1b,
    const float* __restrict__ g2w, const float* __restrict__ g2b,
    const float* __restrict__ g3w, const float* __restrict__ g3b,
    float* __restrict__ gpart) {
  __shared__ float sx[8 * 260];
  __shared__ float sh1[8 * 256];
  __shared__ float sh2[8 * 512];
  int tid = threadIdx.x;
  int p0  = blockIdx.x * 8;

  {
    int p = tid >> 5, c = tid & 31;
    const float4* src = (const float4*)(x2 + (p0 + p) * 256 + c * 8);
    float4 v0 = src[0], v1 = src[1];
    float* dp = sx + p * 260 + c * 8;
    dp[0]=v0.x; dp[1]=v0.y; dp[2]=v0.z; dp[3]=v0.w;
    dp[4]=v1.x; dp[5]=v1.y; dp[6]=v1.z; dp[7]=v1.w;
    if (c < 3) sx[p * 260 + 256 + c] = pos2[(p0 + p) * 3 + c];
  }
  __syncthreads();

  // 259 -> 256 (thread = out channel)
  {
    float acc[8];
#pragma unroll
    for (int p = 0; p < 8; p++) acc[p] = g1b[tid];
    for (int k = 0; k < 259; k++) {
      float wv = g1w[k * 256 + tid];
#pragma unroll
      for (int p = 0; p < 8; p++) acc[p] += sx[p * 260 + k] * wv;
    }
#pragma unroll
    for (int p = 0; p < 8; p++) sh1[p * 256 + tid] = fmaxf(acc[p], 0.f);
  }
  __syncthreads();

  // 256 -> 512 (thread = 2 channels)
  {
    float acc[8][2];
#pragma unroll
    for (int p = 0; p < 8; p++) { acc[p][0] = g2b[tid*2]; acc[p][1] = g2b[tid*2+1]; }
    for (int k = 0; k < 256; k++) {
      float2 wv = *(const float2*)(g2w + k * 512 + tid * 2);
#pragma unroll
      for (int p = 0; p < 8; p++) {
        float a = sh1[p * 256 + k];
        acc[p][0] += a * wv.x; acc[p][1] += a * wv.y;
      }
    }
#pragma unroll
    for (int p = 0; p < 8; p++) {
      sh2[p * 512 + tid*2]   = fmaxf(acc[p][0], 0.f);
      sh2[p * 512 + tid*2+1] = fmaxf(acc[p][1], 0.f);
    }
  }
  __syncthreads();

  // 512 -> 1024 (thread = 4 channels), then max over the 8 points (no relu)
  {
    float acc[8][4];
#pragma unroll
    for (int p = 0; p < 8; p++)
#pragma unroll
      for (int c = 0; c < 4; c++) acc[p][c] = g3b[tid*4 + c];
    for (int k = 0; k < 512; k++) {
      float4 wv = *(const float4*)(g3w + k * 1024 + tid * 4);
#pragma unroll
      for (int p = 0; p < 8; p++) {
        float a = sh2[p * 512 + k];
        acc[p][0] += a * wv.x; acc[p][1] += a * wv.y;
        acc[p][2] += a * wv.z; acc[p][3] += a * wv.w;
      }
    }
    float4 pm;
    pm.x = acc[0][0]; pm.y = acc[0][1]; pm.z = acc[0][2]; pm.w = acc[0][3];
#pragma unroll
    for (int p = 1; p < 8; p++) {
      pm.x = fmaxf(pm.x, acc[p][0]); pm.y = fmaxf(pm.y, acc[p][1]);
      pm.z = fmaxf(pm.z, acc[p][2]); pm.w = fmaxf(pm.w, acc[p][3]);
    }
    *((float4*)(gpart + blockIdx.x * 1024 + tid * 4)) = pm;
  }
}

// ---------------- K4: reduce 16 partials per batch -> g[16][1024] ----------------
__global__ __launch_bounds__(256) void k_pool(const float* __restrict__ gpart,
                                              float* __restrict__ g) {
  int gid = blockIdx.x * 256 + threadIdx.x;  // 16384
  int b = gid >> 10, ch = gid & 1023;
  float m = -INFINITY;
#pragma unroll
  for (int i = 0; i < 16; i++) m = fmaxf(m, gpart[(b * 16 + i) * 1024 + ch]);
  g[gid] = m;
}

// ---------------- head layers ----------------
__global__ __launch_bounds__(256) void k_l1(const float* __restrict__ g,
                                            const float* __restrict__ w,
                                            const float* __restrict__ bias,
                                            float* __restrict__ out) {
  int gid = blockIdx.x * 256 + threadIdx.x;  // 8192
  int b = gid >> 9, j = gid & 511;
  const float* gr = g + b * 1024;
  float acc = bias[j];
  for (int k = 0; k < 1024; k++) acc += gr[k] * w[k * 512 + j];
  out[gid] = fmaxf(acc, 0.f);
}

__global__ __launch_bounds__(256) void k_l2(const float* __restrict__ h,
                                            const float* __restrict__ w,
                                            const float* __restrict__ bias,
                                            float* __restrict__ out) {
  int gid = blockIdx.x * 256 + threadIdx.x;  // 4096
  int b = gid >> 8, j = gid & 255;
  const float* hr = h + b * 512;
  float acc = bias[j];
  for (int k = 0; k < 512; k++) acc += hr[k] * w[k * 256 + j];
  out[gid] = fmaxf(acc, 0.f);
}

__global__ __launch_bounds__(256) void k_l3(const float* __restrict__ h,
                                            const float* __restrict__ w,
                                            const float* __restrict__ bias,
                                            float* __restrict__ out) {
  __shared__ float sl[160];
  int tid = threadIdx.x;
  if (tid < 160) {
    int b = tid / 10, j = tid - b * 10;
    const float* hr = h + b * 256;
    float acc = bias[j];
    for (int k = 0; k < 256; k++) acc += hr[k] * w[k * 10 + j];
    sl[tid] = acc;
  }
  __syncthreads();
  if (tid < 16) {
    float m = -INFINITY;
#pragma unroll
    for (int j = 0; j < 10; j++) m = fmaxf(m, sl[tid * 10 + j]);
    float s = 0.f;
#pragma unroll
    for (int j = 0; j < 10; j++) s += expf(sl[tid * 10 + j] - m);
    float lse = m + logf(s);
#pragma unroll
    for (int j = 0; j < 10; j++) out[tid * 10 + j] = sl[tid * 10 + j] - lse;
  }
}

extern "C" void kernel_launch(void* const* d_in, const int* in_sizes, int n_in,
                              void* d_out, int out_size, void* d_ws, size_t ws_size,
                              hipStream_t stream) {
  (void)in_sizes; (void)n_in; (void)out_size; (void)ws_size;
  const float* pos    = (const float*)d_in[0];
  const int*   idx1   = (const int*)d_in[1];
  const int*   e1_src = (const int*)d_in[2];
  // d_in[3]=e1_dst, d_in[4]=e1_mask: unused (dst = e/64; mask derived from src monotonicity)
  const int*   idx2   = (const int*)d_in[5];
  const int*   e2_src = (const int*)d_in[6];
  // d_in[7]=e2_dst, d_in[8]=e2_mask: unused
  const float* w1a = (const float*)d_in[9],  *b1a = (const float*)d_in[10];
  const float* w1b = (const float*)d_in[11], *b1b = (const float*)d_in[12];
  const float* w1c = (const float*)d_in[13], *b1c = (const float*)d_in[14];
  const float* w2a = (const float*)d_in[15], *b2a = (const float*)d_in[16];
  const float* w2b = (const float*)d_in[17], *b2b = (const float*)d_in[18];
  const float* w2c = (const float*)d_in[19], *b2c = (const float*)d_in[20];
  const float* g1w = (const float*)d_in[21], *g1b = (const float*)d_in[22];
  const float* g2w = (const float*)d_in[23], *g2b = (const float*)d_in[24];
  const float* g3w = (const float*)d_in[25], *g3b = (const float*)d_in[26];
  const float* l1w = (const float*)d_in[27], *l1b = (const float*)d_in[28];
  const float* l2w = (const float*)d_in[29], *l2b = (const float*)d_in[30];
  const float* l3w = (const float*)d_in[31], *l3b = (const float*)d_in[32];

  float* ws    = (float*)d_ws;
  float* pos1  = ws + POS1_OFF;
  float* pos2  = ws + POS2_OFF;
  float* x1    = ws + X1_OFF;
  float* x2    = ws + X2_OFF;
  float* gpart = ws + GPART_OFF;
  float* g     = ws + G_OFF;
  float* h1    = ws + H1_OFF;
  float* h2    = ws + H2_OFF;

  k_gather<<<(N1 + N2 + 255) / 256, 256, 0, stream>>>(pos, idx1, idx2, pos1, pos2);
  k_conv1<<<N1, 256, 0, stream>>>(pos, pos1, e1_src, w1a, b1a, w1b, b1b, w1c, b1c, x1);
  k_conv2<<<N2, 256, 0, stream>>>(pos1, pos2, e2_src, x1, w2a, b2a, w2b, b2b, w2c, b2c, x2);
  k_gmlp<<<256, 256, 0, stream>>>(x2, pos2, g1w, g1b, g2w, g2b, g3w, g3b, gpart);
  k_pool<<<64, 256, 0, stream>>>(gpart, g);
  k_l1<<<32, 256, 0, stream>>>(g, l1w, l1b, h1);
  k_l2<<<16, 256, 0, stream>>>(h1, l2w, l2b, h2);
  k_l3<<<1, 256, 0, stream>>>(h2, l3w, l3b, (float*)d_out);
}

// Round 2
// 358.543 us; speedup vs baseline: 2.1027x; 2.1027x over previous
//
#include <hip/hip_runtime.h>
#include <hip/hip_bf16.h>
#include <math.h>

#define NBATCH 16
#define S1     512
#define S2     128
#define MAXN   64
#define N1     8192   /* NBATCH*S1 */
#define N2     2048   /* NBATCH*S2 */

// ---------------- workspace layout ----------------
// float region (offsets in floats):
#define POS1_OFF  0           /* 8192*3   = 24576  */
#define POS2_OFF  24576       /* 2048*3   = 6144   */
#define X2_OFF    30720       /* 2048*256 = 524288 */
#define GPART_OFF 555008      /* 256*1024 = 262144 */
#define G_OFF     817152      /* 16*1024  = 16384  */
#define H1_OFF    833536      /* 16*512   = 8192   */
#define H2_OFF    841728      /* 16*256   = 4096   */
#define FLT_END   845824
// bf16(short) region, base = (short*)(ws + FLT_END), offsets in shorts:
#define X1B_OFF   0           /* 8192*128 = 1048576 */
#define WT1A_OFF  1048576     /* [64][32]   = 2048  */
#define WT1B_OFF  1050624     /* [64][64]   = 4096  */
#define WT1C_OFF  1054720     /* [128][64]  = 8192  */
#define WT2A_OFF  1062912     /* [128][160] = 20480 */
#define WT2B_OFF  1083392     /* [128][128] = 16384 */
#define WT2C_OFF  1099776     /* [256][128] = 32768 */
/* total shorts 1132544 -> ws usage ~5.65 MB (round-0 used 7.6 MB OK) */

typedef __attribute__((ext_vector_type(8))) short bf16x8;
typedef __attribute__((ext_vector_type(4))) float f32x4;

static __device__ __forceinline__ short f2bs(float f) {
  __hip_bfloat16 b = __float2bfloat16(f);
  return __builtin_bit_cast(short, b);
}

// ---------------- K_prep: weights -> bf16, transposed [N][K], zero-padded ----------------
__global__ __launch_bounds__(256) void k_prep(
    const float* __restrict__ w1a, const float* __restrict__ w1b, const float* __restrict__ w1c,
    const float* __restrict__ w2a, const float* __restrict__ w2b, const float* __restrict__ w2c,
    short* __restrict__ wt1a, short* __restrict__ wt1b, short* __restrict__ wt1c,
    short* __restrict__ wt2a, short* __restrict__ wt2b, short* __restrict__ wt2c) {
  int t = blockIdx.x * 256 + threadIdx.x;
  if (t < 2048) { int n = t >> 5, k = t & 31; wt1a[t] = f2bs(k < 3 ? w1a[k*64 + n] : 0.f); return; }
  t -= 2048;
  if (t < 4096) { int n = t >> 6, k = t & 63; wt1b[t] = f2bs(w1b[k*64 + n]); return; }
  t -= 4096;
  if (t < 8192) { int n = t >> 6, k = t & 63; wt1c[t] = f2bs(w1c[k*128 + n]); return; }
  t -= 8192;
  if (t < 20480) { int n = t / 160, k = t - n*160; wt2a[t] = f2bs(k < 131 ? w2a[k*128 + n] : 0.f); return; }
  t -= 20480;
  if (t < 16384) { int n = t >> 7, k = t & 127; wt2b[t] = f2bs(w2b[k*128 + n]); return; }
  t -= 16384;
  if (t < 32768) { int n = t >> 7, k = t & 127; wt2c[t] = f2bs(w2c[k*256 + n]); return; }
}

// ---------------- K0: gather pos1 = pos[idx1], pos2 = pos[idx1[idx2]] ----------------
__global__ __launch_bounds__(256) void k_gather(const float* __restrict__ pos,
                                                const int* __restrict__ idx1,
                                                const int* __restrict__ idx2,
                                                float* __restrict__ pos1,
                                                float* __restrict__ pos2) {
  int i = blockIdx.x * 256 + threadIdx.x;
  if (i < N1) {
    int s = idx1[i];
    pos1[i*3+0] = pos[s*3+0]; pos1[i*3+1] = pos[s*3+1]; pos1[i*3+2] = pos[s*3+2];
  } else if (i < N1 + N2) {
    int j = i - N1;
    int s = idx1[idx2[j]];
    pos2[j*3+0] = pos[s*3+0]; pos2[j*3+1] = pos[s*3+1]; pos2[j*3+2] = pos[s*3+2];
  }
}

// ---------------- K1: conv1 MFMA  (rel(3,pad32) -> 64 -> 64 -> 128, segmax) ----------------
// block = 1 segment (64 edges), 4 waves; wave w owns an N-slice. mfma 16x16x32 bf16.
// A-frag: lane reads feat[mt*16 + (lane&15)][(lane>>4)*8 + ks*32 ..+8]
// B-frag: lane reads wT[ntile*16 + (lane&15)][(lane>>4)*8 + ks*32 ..+8]
// C/D: col = lane&15 (channel), row = (lane>>4)*4 + r (edge)  [m89-verified layout]
// LDS row strides chosen so stride_bytes/4 mod 32 in {4,20} -> conflict-free b128 reads.
__global__ __launch_bounds__(256) void k_conv1(
    const float* __restrict__ pos, const float* __restrict__ pos1,
    const int* __restrict__ esrc,
    const short* __restrict__ wt1a, const float* __restrict__ b1a,
    const short* __restrict__ wt1b, const float* __restrict__ b1b,
    const short* __restrict__ wt1c, const float* __restrict__ b1c,
    short* __restrict__ x1b) {
  __shared__ __align__(16) short sA[64 * 40];  // feat, K=32 pad, stride 40 (80B: 20 mod 32 ok)
  __shared__ __align__(16) short sB[64 * 72];  // hA,  K=64, stride 72 (144B: 4 mod 32 ok)
  __shared__ __align__(16) short sC[64 * 72];  // hB
  __shared__ short sval[64];

  int seg = blockIdx.x, tid = threadIdx.x;
  int lane = tid & 63;
  int w  = tid >> 6;
  int lr = lane & 15;
  int lg = lane >> 4;

  if (tid < 64) {
    int e = seg * 64 + tid;
    int s = esrc[e];
    sval[tid] = (short)((tid == 0) || (s > esrc[e - 1]));
    short* row = sA + tid * 40;
    row[0] = f2bs(pos[s*3+0] - pos1[seg*3+0]);
    row[1] = f2bs(pos[s*3+1] - pos1[seg*3+1]);
    row[2] = f2bs(pos[s*3+2] - pos1[seg*3+2]);
#pragma unroll
    for (int i = 3; i < 40; i++) row[i] = 0;
  }
  __syncthreads();

  // layer A: K=32 (1 kstep), wave w -> ch [w*16, w*16+16)
  {
    f32x4 acc[4];
#pragma unroll
    for (int mt = 0; mt < 4; mt++) acc[mt] = (f32x4){0.f, 0.f, 0.f, 0.f};
    bf16x8 bf = *(const bf16x8*)(wt1a + (w*16 + lr) * 32 + lg * 8);
#pragma unroll
    for (int mt = 0; mt < 4; mt++) {
      bf16x8 af = *(const bf16x8*)(sA + (mt*16 + lr) * 40 + lg * 8);
      acc[mt] = __builtin_amdgcn_mfma_f32_16x16x32_bf16(af, bf, acc[mt], 0, 0, 0);
    }
    float bias = b1a[w*16 + lr];
#pragma unroll
    for (int mt = 0; mt < 4; mt++)
#pragma unroll
      for (int r = 0; r < 4; r++)
        sB[(mt*16 + lg*4 + r) * 72 + w*16 + lr] = f2bs(fmaxf(acc[mt][r] + bias, 0.f));
  }
  __syncthreads();

  // layer B: K=64 (2 ksteps), ch [w*16, w*16+16)
  {
    f32x4 acc[4];
#pragma unroll
    for (int mt = 0; mt < 4; mt++) acc[mt] = (f32x4){0.f, 0.f, 0.f, 0.f};
#pragma unroll
    for (int ks = 0; ks < 2; ks++) {
      bf16x8 bf = *(const bf16x8*)(wt1b + (w*16 + lr) * 64 + ks*32 + lg * 8);
#pragma unroll
      for (int mt = 0; mt < 4; mt++) {
        bf16x8 af = *(const bf16x8*)(sB + (mt*16 + lr) * 72 + ks*32 + lg * 8);
        acc[mt] = __builtin_amdgcn_mfma_f32_16x16x32_bf16(af, bf, acc[mt], 0, 0, 0);
      }
    }
    float bias = b1b[w*16 + lr];
#pragma unroll
    for (int mt = 0; mt < 4; mt++)
#pragma unroll
      for (int r = 0; r < 4; r++)
        sC[(mt*16 + lg*4 + r) * 72 + w*16 + lr] = f2bs(fmaxf(acc[mt][r] + bias, 0.f));
  }
  __syncthreads();

  // layer C: K=64, N=128 -> wave w owns ch [w*32, w*32+32), 2 ntiles; segmax via acc-init mask
  {
    f32x4 acc[4][2];
#pragma unroll
    for (int mt = 0; mt < 4; mt++) {
      f32x4 vi;
#pragma unroll
      for (int r = 0; r < 4; r++) vi[r] = sval[mt*16 + lg*4 + r] ? 0.f : -1e30f;
      acc[mt][0] = vi; acc[mt][1] = vi;
    }
#pragma unroll
    for (int ks = 0; ks < 2; ks++) {
      bf16x8 bf0 = *(const bf16x8*)(wt1c + (w*32 + lr)      * 64 + ks*32 + lg * 8);
      bf16x8 bf1 = *(const bf16x8*)(wt1c + (w*32 + 16 + lr) * 64 + ks*32 + lg * 8);
#pragma unroll
      for (int mt = 0; mt < 4; mt++) {
        bf16x8 af = *(const bf16x8*)(sC + (mt*16 + lr) * 72 + ks*32 + lg * 8);
        acc[mt][0] = __builtin_amdgcn_mfma_f32_16x16x32_bf16(af, bf0, acc[mt][0], 0, 0, 0);
        acc[mt][1] = __builtin_amdgcn_mfma_f32_16x16x32_bf16(af, bf1, acc[mt][1], 0, 0, 0);
      }
    }
#pragma unroll
    for (int nt = 0; nt < 2; nt++) {
      float m = -3e38f;
#pragma unroll
      for (int mt = 0; mt < 4; mt++)
#pragma unroll
        for (int r = 0; r < 4; r++) m = fmaxf(m, acc[mt][nt][r]);
      m = fmaxf(m, __shfl_xor(m, 16, 64));
      m = fmaxf(m, __shfl_xor(m, 32, 64));
      if (lg == 0) {
        int ch = w*32 + nt*16 + lr;
        x1b[seg*128 + ch] = f2bs(fmaxf(m + b1c[ch], 0.f));
      }
    }
  }
}

// ---------------- K2: conv2 MFMA ([x1(128),rel(3)] pad160 -> 128 -> 128 -> 256, segmax) ----
__global__ __launch_bounds__(256) void k_conv2(
    const float* __restrict__ pos1, const float* __restrict__ pos2,
    const int* __restrict__ esrc, const short* __restrict__ x1b,
    const short* __restrict__ wt2a, const float* __restrict__ b2a,
    const short* __restrict__ wt2b, const float* __restrict__ b2b,
    const short* __restrict__ wt2c, const float* __restrict__ b2c,
    float* __restrict__ x2) {
  __shared__ __align__(16) short sX[64 * 168]; // feat K=160, stride 168 (336B: 20 mod 32 ok); reused as hB stride 136
  __shared__ __align__(16) short sY[64 * 136]; // hA, K=128, stride 136 (272B: 4 mod 32 ok)
  __shared__ short sval[64];

  int seg = blockIdx.x, tid = threadIdx.x;
  int lane = tid & 63;
  int w  = tid >> 6;
  int lr = lane & 15;
  int lg = lane >> 4;

  // stage feat = [x1b[src] (bf16 x 128), rel(3), zeros]
  {
    int e = tid >> 2, q = tid & 3;
    int s = esrc[seg*64 + e];
    const uint4* src = (const uint4*)(x1b + s * 128) + q * 4;
    uint4* dst = (uint4*)(sX + e * 168 + q * 32);
#pragma unroll
    for (int i = 0; i < 4; i++) dst[i] = src[i];
  }
  if (tid < 64) {
    int e = seg * 64 + tid;
    int s = esrc[e];
    sval[tid] = (short)((tid == 0) || (s > esrc[e - 1]));
    short* row = sX + tid * 168;
    row[128] = f2bs(pos1[s*3+0] - pos2[seg*3+0]);
    row[129] = f2bs(pos1[s*3+1] - pos2[seg*3+1]);
    row[130] = f2bs(pos1[s*3+2] - pos2[seg*3+2]);
#pragma unroll
    for (int i = 131; i < 168; i++) row[i] = 0;
  }
  __syncthreads();

  // layer A: K=160 (5 ksteps), wave w -> ch [w*32, +32), 2 ntiles; read sX(168), write sY(136)
  {
    f32x4 acc[4][2];
#pragma unroll
    for (int mt = 0; mt < 4; mt++) { acc[mt][0] = (f32x4){0.f,0.f,0.f,0.f}; acc[mt][1] = (f32x4){0.f,0.f,0.f,0.f}; }
#pragma unroll
    for (int ks = 0; ks < 5; ks++) {
      bf16x8 bf0 = *(const bf16x8*)(wt2a + (w*32 + lr)      * 160 + ks*32 + lg * 8);
      bf16x8 bf1 = *(const bf16x8*)(wt2a + (w*32 + 16 + lr) * 160 + ks*32 + lg * 8);
#pragma unroll
      for (int mt = 0; mt < 4; mt++) {
        bf16x8 af = *(const bf16x8*)(sX + (mt*16 + lr) * 168 + ks*32 + lg * 8);
        acc[mt][0] = __builtin_amdgcn_mfma_f32_16x16x32_bf16(af, bf0, acc[mt][0], 0, 0, 0);
        acc[mt][1] = __builtin_amdgcn_mfma_f32_16x16x32_bf16(af, bf1, acc[mt][1], 0, 0, 0);
      }
    }
    float bias0 = b2a[w*32 + lr], bias1 = b2a[w*32 + 16 + lr];
#pragma unroll
    for (int mt = 0; mt < 4; mt++)
#pragma unroll
      for (int r = 0; r < 4; r++) {
        int row = mt*16 + lg*4 + r;
        sY[row * 136 + w*32 + lr]      = f2bs(fmaxf(acc[mt][0][r] + bias0, 0.f));
        sY[row * 136 + w*32 + 16 + lr] = f2bs(fmaxf(acc[mt][1][r] + bias1, 0.f));
      }
  }
  __syncthreads();

  // layer B: K=128 (4 ksteps), ch [w*32,+32); read sY(136), write sX reused stride 136
  {
    f32x4 acc[4][2];
#pragma unroll
    for (int mt = 0; mt < 4; mt++) { acc[mt][0] = (f32x4){0.f,0.f,0.f,0.f}; acc[mt][1] = (f32x4){0.f,0.f,0.f,0.f}; }
#pragma unroll
    for (int ks = 0; ks < 4; ks++) {
      bf16x8 bf0 = *(const bf16x8*)(wt2b + (w*32 + lr)      * 128 + ks*32 + lg * 8);
      bf16x8 bf1 = *(const bf16x8*)(wt2b + (w*32 + 16 + lr) * 128 + ks*32 + lg * 8);
#pragma unroll
      for (int mt = 0; mt < 4; mt++) {
        bf16x8 af = *(const bf16x8*)(sY + (mt*16 + lr) * 136 + ks*32 + lg * 8);
        acc[mt][0] = __builtin_amdgcn_mfma_f32_16x16x32_bf16(af, bf0, acc[mt][0], 0, 0, 0);
        acc[mt][1] = __builtin_amdgcn_mfma_f32_16x16x32_bf16(af, bf1, acc[mt][1], 0, 0, 0);
      }
    }
    float bias0 = b2b[w*32 + lr], bias1 = b2b[w*32 + 16 + lr];
#pragma unroll
    for (int mt = 0; mt < 4; mt++)
#pragma unroll
      for (int r = 0; r < 4; r++) {
        int row = mt*16 + lg*4 + r;
        sX[row * 136 + w*32 + lr]      = f2bs(fmaxf(acc[mt][0][r] + bias0, 0.f));
        sX[row * 136 + w*32 + 16 + lr] = f2bs(fmaxf(acc[mt][1][r] + bias1, 0.f));
      }
  }
  __syncthreads();

  // layer C: K=128, N=256 -> wave w owns ch [w*64,+64), 4 ntiles; segmax via acc-init mask
  {
    f32x4 acc[4][4];
#pragma unroll
    for (int mt = 0; mt < 4; mt++) {
      f32x4 vi;
#pragma unroll
      for (int r = 0; r < 4; r++) vi[r] = sval[mt*16 + lg*4 + r] ? 0.f : -1e30f;
#pragma unroll
      for (int nt = 0; nt < 4; nt++) acc[mt][nt] = vi;
    }
#pragma unroll
    for (int ks = 0; ks < 4; ks++) {
      bf16x8 bfr[4];
#pragma unroll
      for (int nt = 0; nt < 4; nt++)
        bfr[nt] = *(const bf16x8*)(wt2c + (w*64 + nt*16 + lr) * 128 + ks*32 + lg * 8);
#pragma unroll
      for (int mt = 0; mt < 4; mt++) {
        bf16x8 af = *(const bf16x8*)(sX + (mt*16 + lr) * 136 + ks*32 + lg * 8);
#pragma unroll
        for (int nt = 0; nt < 4; nt++)
          acc[mt][nt] = __builtin_amdgcn_mfma_f32_16x16x32_bf16(af, bfr[nt], acc[mt][nt], 0, 0, 0);
      }
    }
#pragma unroll
    for (int nt = 0; nt < 4; nt++) {
      float m = -3e38f;
#pragma unroll
      for (int mt = 0; mt < 4; mt++)
#pragma unroll
        for (int r = 0; r < 4; r++) m = fmaxf(m, acc[mt][nt][r]);
      m = fmaxf(m, __shfl_xor(m, 16, 64));
      m = fmaxf(m, __shfl_xor(m, 32, 64));
      if (lg == 0) {
        int ch = w*64 + nt*16 + lr;
        x2[seg*256 + ch] = fmaxf(m + b2c[ch], 0.f);
      }
    }
  }
}

// ---------------- K3: g-MLP (259 -> 256 -> 512 -> 1024) + partial max over 8 points ----
__global__ __launch_bounds__(256) void k_gmlp(
    const float* __restrict__ x2, const float* __restrict__ pos2,
    const float* __restrict__ g1w, const float* __restrict__ g1b,
    const float* __restrict__ g2w, const float* __restrict__ g2b,
    const float* __restrict__ g3w, const float* __restrict__ g3b,
    float* __restrict__ gpart) {
  __shared__ float sx[8 * 260];
  __shared__ float sh1[8 * 256];
  __shared__ float sh2[8 * 512];
  int tid = threadIdx.x;
  int p0  = blockIdx.x * 8;

  {
    int p = tid >> 5, c = tid & 31;
    const float4* src = (const float4*)(x2 + (p0 + p) * 256 + c * 8);
    float4 v0 = src[0], v1 = src[1];
    float* dp = sx + p * 260 + c * 8;
    dp[0]=v0.x; dp[1]=v0.y; dp[2]=v0.z; dp[3]=v0.w;
    dp[4]=v1.x; dp[5]=v1.y; dp[6]=v1.z; dp[7]=v1.w;
    if (c < 3) sx[p * 260 + 256 + c] = pos2[(p0 + p) * 3 + c];
  }
  __syncthreads();

  {
    float acc[8];
#pragma unroll
    for (int p = 0; p < 8; p++) acc[p] = g1b[tid];
    for (int k = 0; k < 259; k++) {
      float wv = g1w[k * 256 + tid];
#pragma unroll
      for (int p = 0; p < 8; p++) acc[p] += sx[p * 260 + k] * wv;
    }
#pragma unroll
    for (int p = 0; p < 8; p++) sh1[p * 256 + tid] = fmaxf(acc[p], 0.f);
  }
  __syncthreads();

  {
    float acc[8][2];
#pragma unroll
    for (int p = 0; p < 8; p++) { acc[p][0] = g2b[tid*2]; acc[p][1] = g2b[tid*2+1]; }
    for (int k = 0; k < 256; k++) {
      float2 wv = *(const float2*)(g2w + k * 512 + tid * 2);
#pragma unroll
      for (int p = 0; p < 8; p++) {
        float a = sh1[p * 256 + k];
        acc[p][0] += a * wv.x; acc[p][1] += a * wv.y;
      }
    }
#pragma unroll
    for (int p = 0; p < 8; p++) {
      sh2[p * 512 + tid*2]   = fmaxf(acc[p][0], 0.f);
      sh2[p * 512 + tid*2+1] = fmaxf(acc[p][1], 0.f);
    }
  }
  __syncthreads();

  {
    float acc[8][4];
#pragma unroll
    for (int p = 0; p < 8; p++)
#pragma unroll
      for (int c = 0; c < 4; c++) acc[p][c] = g3b[tid*4 + c];
    for (int k = 0; k < 512; k++) {
      float4 wv = *(const float4*)(g3w + k * 1024 + tid * 4);
#pragma unroll
      for (int p = 0; p < 8; p++) {
        float a = sh2[p * 512 + k];
        acc[p][0] += a * wv.x; acc[p][1] += a * wv.y;
        acc[p][2] += a * wv.z; acc[p][3] += a * wv.w;
      }
    }
    float4 pm;
    pm.x = acc[0][0]; pm.y = acc[0][1]; pm.z = acc[0][2]; pm.w = acc[0][3];
#pragma unroll
    for (int p = 1; p < 8; p++) {
      pm.x = fmaxf(pm.x, acc[p][0]); pm.y = fmaxf(pm.y, acc[p][1]);
      pm.z = fmaxf(pm.z, acc[p][2]); pm.w = fmaxf(pm.w, acc[p][3]);
    }
    *((float4*)(gpart + blockIdx.x * 1024 + tid * 4)) = pm;
  }
}

// ---------------- K4: reduce 16 partials per batch -> g[16][1024] ----------------
__global__ __launch_bounds__(256) void k_pool(const float* __restrict__ gpart,
                                              float* __restrict__ g) {
  int gid = blockIdx.x * 256 + threadIdx.x;
  int b = gid >> 10, ch = gid & 1023;
  float m = -INFINITY;
#pragma unroll
  for (int i = 0; i < 16; i++) m = fmaxf(m, gpart[(b * 16 + i) * 1024 + ch]);
  g[gid] = m;
}

// ---------------- head layers ----------------
__global__ __launch_bounds__(256) void k_l1(const float* __restrict__ g,
                                            const float* __restrict__ w,
                                            const float* __restrict__ bias,
                                            float* __restrict__ out) {
  int gid = blockIdx.x * 256 + threadIdx.x;
  int b = gid >> 9, j = gid & 511;
  const float* gr = g + b * 1024;
  float acc = bias[j];
  for (int k = 0; k < 1024; k++) acc += gr[k] * w[k * 512 + j];
  out[gid] = fmaxf(acc, 0.f);
}

__global__ __launch_bounds__(256) void k_l2(const float* __restrict__ h,
                                            const float* __restrict__ w,
                                            const float* __restrict__ bias,
                                            float* __restrict__ out) {
  int gid = blockIdx.x * 256 + threadIdx.x;
  int b = gid >> 8, j = gid & 255;
  const float* hr = h + b * 512;
  float acc = bias[j];
  for (int k = 0; k < 512; k++) acc += hr[k] * w[k * 256 + j];
  out[gid] = fmaxf(acc, 0.f);
}

__global__ __launch_bounds__(256) void k_l3(const float* __restrict__ h,
                                            const float* __restrict__ w,
                                            const float* __restrict__ bias,
                                            float* __restrict__ out) {
  __shared__ float sl[160];
  int tid = threadIdx.x;
  if (tid < 160) {
    int b = tid / 10, j = tid - b * 10;
    const float* hr = h + b * 256;
    float acc = bias[j];
    for (int k = 0; k < 256; k++) acc += hr[k] * w[k * 10 + j];
    sl[tid] = acc;
  }
  __syncthreads();
  if (tid < 16) {
    float m = -INFINITY;
#pragma unroll
    for (int j = 0; j < 10; j++) m = fmaxf(m, sl[tid * 10 + j]);
    float s = 0.f;
#pragma unroll
    for (int j = 0; j < 10; j++) s += expf(sl[tid * 10 + j] - m);
    float lse = m + logf(s);
#pragma unroll
    for (int j = 0; j < 10; j++) out[tid * 10 + j] = sl[tid * 10 + j] - lse;
  }
}

extern "C" void kernel_launch(void* const* d_in, const int* in_sizes, int n_in,
                              void* d_out, int out_size, void* d_ws, size_t ws_size,
                              hipStream_t stream) {
  (void)in_sizes; (void)n_in; (void)out_size; (void)ws_size;
  const float* pos    = (const float*)d_in[0];
  const int*   idx1   = (const int*)d_in[1];
  const int*   e1_src = (const int*)d_in[2];
  const int*   idx2   = (const int*)d_in[5];
  const int*   e2_src = (const int*)d_in[6];
  const float* w1a = (const float*)d_in[9],  *b1a = (const float*)d_in[10];
  const float* w1b = (const float*)d_in[11], *b1b = (const float*)d_in[12];
  const float* w1c = (const float*)d_in[13], *b1c = (const float*)d_in[14];
  const float* w2a = (const float*)d_in[15], *b2a = (const float*)d_in[16];
  const float* w2b = (const float*)d_in[17], *b2b = (const float*)d_in[18];
  const float* w2c = (const float*)d_in[19], *b2c = (const float*)d_in[20];
  const float* g1w = (const float*)d_in[21], *g1b = (const float*)d_in[22];
  const float* g2w = (const float*)d_in[23], *g2b = (const float*)d_in[24];
  const float* g3w = (const float*)d_in[25], *g3b = (const float*)d_in[26];
  const float* l1w = (const float*)d_in[27], *l1b = (const float*)d_in[28];
  const float* l2w = (const float*)d_in[29], *l2b = (const float*)d_in[30];
  const float* l3w = (const float*)d_in[31], *l3b = (const float*)d_in[32];

  float* ws    = (float*)d_ws;
  float* pos1  = ws + POS1_OFF;
  float* pos2  = ws + POS2_OFF;
  float* x2    = ws + X2_OFF;
  float* gpart = ws + GPART_OFF;
  float* g     = ws + G_OFF;
  float* h1    = ws + H1_OFF;
  float* h2    = ws + H2_OFF;
  short* sbase = (short*)(ws + FLT_END);
  short* x1b   = sbase + X1B_OFF;
  short* wt1a  = sbase + WT1A_OFF;
  short* wt1b  = sbase + WT1B_OFF;
  short* wt1c  = sbase + WT1C_OFF;
  short* wt2a  = sbase + WT2A_OFF;
  short* wt2b  = sbase + WT2B_OFF;
  short* wt2c  = sbase + WT2C_OFF;

  k_prep<<<328, 256, 0, stream>>>(w1a, w1b, w1c, w2a, w2b, w2c,
                                  wt1a, wt1b, wt1c, wt2a, wt2b, wt2c);
  k_gather<<<(N1 + N2 + 255) / 256, 256, 0, stream>>>(pos, idx1, idx2, pos1, pos2);
  k_conv1<<<N1, 256, 0, stream>>>(pos, pos1, e1_src, wt1a, b1a, wt1b, b1b, wt1c, b1c, x1b);
  k_conv2<<<N2, 256, 0, stream>>>(pos1, pos2, e2_src, x1b, wt2a, b2a, wt2b, b2b, wt2c, b2c, x2);
  k_gmlp<<<256, 256, 0, stream>>>(x2, pos2, g1w, g1b, g2w, g2b, g3w, g3b, gpart);
  k_pool<<<64, 256, 0, stream>>>(gpart, g);
  k_l1<<<32, 256, 0, stream>>>(g, l1w, l1b, h1);
  k_l2<<<16, 256, 0, stream>>>(h1, l2w, l2b, h2);
  k_l3<<<1, 256, 0, stream>>>(h2, l3w, l3b, (float*)d_out);
}

// Round 3
// 301.510 us; speedup vs baseline: 2.5005x; 1.1892x over previous
//
#include <hip/hip_runtime.h>
#include <hip/hip_bf16.h>
#include <math.h>

#define NBATCH 16
#define S1     512
#define S2     128
#define MAXN   64
#define N1     8192   /* NBATCH*S1 */
#define N2     2048   /* NBATCH*S2 */

// ---------------- workspace layout ----------------
// float region (offsets in floats):
#define POS1_OFF  0           /* 8192*3  = 24576 */
#define POS2_OFF  24576       /* 2048*3  = 6144  */
#define GPART_OFF 30720       /* 32*1024 = 32768 */
#define G_OFF     63488       /* 16*1024 = 16384 */
#define H1H_OFF   79872       /* 16*512  = 8192  */
#define H2H_OFF   88064       /* 16*256  = 4096  */
#define FLT_END   92160
// bf16(short) region, base = (short*)(ws + FLT_END), offsets in shorts:
#define X1B_OFF   0           /* 8192*128  = 1048576 */
#define XG_OFF    1048576     /* 2048*288  = 589824  */
#define H1_OFF    1638400     /* 2048*256  = 524288  */
#define H2_OFF    2162688     /* 2048*512  = 1048576 */
#define WT1A_OFF  3211264     /* [64][32]   = 2048  */
#define WT1B_OFF  3213312     /* [64][64]   = 4096  */
#define WT1C_OFF  3217408     /* [128][64]  = 8192  */
#define WT2A_OFF  3225600     /* [128][160] = 20480 */
#define WT2B_OFF  3246080     /* [128][128] = 16384 */
#define WT2C_OFF  3262464     /* [256][128] = 32768 */
#define GT1_OFF   3295232     /* [256][288] = 73728  */
#define GT2_OFF   3368960     /* [512][256] = 131072 */
#define GT3_OFF   3500032     /* [1024][512]= 524288 */
/* end 4024320 shorts -> total ws ~8.42 MB */

typedef __attribute__((ext_vector_type(8))) short bf16x8;
typedef __attribute__((ext_vector_type(4))) float f32x4;

static __device__ __forceinline__ short f2bs(float f) {
  __hip_bfloat16 b = __float2bfloat16(f);
  return __builtin_bit_cast(short, b);
}

// ---------------- K_prep: all weights -> bf16, transposed [N][Kpad], zero-padded --------
__global__ __launch_bounds__(256) void k_prep(
    const float* __restrict__ w1a, const float* __restrict__ w1b, const float* __restrict__ w1c,
    const float* __restrict__ w2a, const float* __restrict__ w2b, const float* __restrict__ w2c,
    const float* __restrict__ g1w, const float* __restrict__ g2w, const float* __restrict__ g3w,
    short* __restrict__ wt1a, short* __restrict__ wt1b, short* __restrict__ wt1c,
    short* __restrict__ wt2a, short* __restrict__ wt2b, short* __restrict__ wt2c,
    short* __restrict__ gt1,  short* __restrict__ gt2,  short* __restrict__ gt3) {
  int t = blockIdx.x * 256 + threadIdx.x;
  if (t < 2048) { int n = t >> 5, k = t & 31; wt1a[t] = f2bs(k < 3 ? w1a[k*64 + n] : 0.f); return; }
  t -= 2048;
  if (t < 4096) { int n = t >> 6, k = t & 63; wt1b[t] = f2bs(w1b[k*64 + n]); return; }
  t -= 4096;
  if (t < 8192) { int n = t >> 6, k = t & 63; wt1c[t] = f2bs(w1c[k*128 + n]); return; }
  t -= 8192;
  if (t < 20480) { int n = t / 160, k = t - n*160; wt2a[t] = f2bs(k < 131 ? w2a[k*128 + n] : 0.f); return; }
  t -= 20480;
  if (t < 16384) { int n = t >> 7, k = t & 127; wt2b[t] = f2bs(w2b[k*128 + n]); return; }
  t -= 16384;
  if (t < 32768) { int n = t >> 7, k = t & 127; wt2c[t] = f2bs(w2c[k*256 + n]); return; }
  t -= 32768;
  if (t < 73728) { int n = t / 288, k = t - n*288; gt1[t] = f2bs(k < 259 ? g1w[k*256 + n] : 0.f); return; }
  t -= 73728;
  if (t < 131072) { int n = t >> 8, k = t & 255; gt2[t] = f2bs(g2w[k*512 + n]); return; }
  t -= 131072;
  if (t < 524288) { int n = t >> 9, k = t & 511; gt3[t] = f2bs(g3w[k*1024 + n]); return; }
}

// ---------------- K0: gather pos1/pos2 + xg pos columns & pad ----------------
__global__ __launch_bounds__(256) void k_gather(const float* __restrict__ pos,
                                                const int* __restrict__ idx1,
                                                const int* __restrict__ idx2,
                                                float* __restrict__ pos1,
                                                float* __restrict__ pos2,
                                                short* __restrict__ xg) {
  int i = blockIdx.x * 256 + threadIdx.x;
  if (i < N1) {
    int s = idx1[i];
    pos1[i*3+0] = pos[s*3+0]; pos1[i*3+1] = pos[s*3+1]; pos1[i*3+2] = pos[s*3+2];
  } else if (i < N1 + N2) {
    int j = i - N1;
    int s = idx1[idx2[j]];
    float p0 = pos[s*3+0], p1 = pos[s*3+1], p2 = pos[s*3+2];
    pos2[j*3+0] = p0; pos2[j*3+1] = p1; pos2[j*3+2] = p2;
    short* row = xg + j * 288;
    row[256] = f2bs(p0); row[257] = f2bs(p1); row[258] = f2bs(p2);
#pragma unroll
    for (int c = 259; c < 288; c++) row[c] = 0;
  }
}

// ---------------- K1: conv1 MFMA (rel(3,pad32) -> 64 -> 64 -> 128, segmax) ----------------
__global__ __launch_bounds__(256) void k_conv1(
    const float* __restrict__ pos, const float* __restrict__ pos1,
    const int* __restrict__ esrc,
    const short* __restrict__ wt1a, const float* __restrict__ b1a,
    const short* __restrict__ wt1b, const float* __restrict__ b1b,
    const short* __restrict__ wt1c, const float* __restrict__ b1c,
    short* __restrict__ x1b) {
  __shared__ __align__(16) short sA[64 * 40];
  __shared__ __align__(16) short sB[64 * 72];
  __shared__ __align__(16) short sC[64 * 72];
  __shared__ short sval[64];

  int seg = blockIdx.x, tid = threadIdx.x;
  int lane = tid & 63;
  int w  = tid >> 6;
  int lr = lane & 15;
  int lg = lane >> 4;

  if (tid < 64) {
    int e = seg * 64 + tid;
    int s = esrc[e];
    sval[tid] = (short)((tid == 0) || (s > esrc[e - 1]));
    short* row = sA + tid * 40;
    row[0] = f2bs(pos[s*3+0] - pos1[seg*3+0]);
    row[1] = f2bs(pos[s*3+1] - pos1[seg*3+1]);
    row[2] = f2bs(pos[s*3+2] - pos1[seg*3+2]);
#pragma unroll
    for (int i = 3; i < 40; i++) row[i] = 0;
  }
  __syncthreads();

  // layer A: K=32, wave w -> ch [w*16,+16)
  {
    f32x4 acc[4];
#pragma unroll
    for (int mt = 0; mt < 4; mt++) acc[mt] = (f32x4){0.f, 0.f, 0.f, 0.f};
    bf16x8 bf = *(const bf16x8*)(wt1a + (w*16 + lr) * 32 + lg * 8);
#pragma unroll
    for (int mt = 0; mt < 4; mt++) {
      bf16x8 af = *(const bf16x8*)(sA + (mt*16 + lr) * 40 + lg * 8);
      acc[mt] = __builtin_amdgcn_mfma_f32_16x16x32_bf16(af, bf, acc[mt], 0, 0, 0);
    }
    float bias = b1a[w*16 + lr];
#pragma unroll
    for (int mt = 0; mt < 4; mt++)
#pragma unroll
      for (int r = 0; r < 4; r++)
        sB[(mt*16 + lg*4 + r) * 72 + w*16 + lr] = f2bs(fmaxf(acc[mt][r] + bias, 0.f));
  }
  __syncthreads();

  // layer B: K=64
  {
    f32x4 acc[4];
#pragma unroll
    for (int mt = 0; mt < 4; mt++) acc[mt] = (f32x4){0.f, 0.f, 0.f, 0.f};
#pragma unroll
    for (int ks = 0; ks < 2; ks++) {
      bf16x8 bf = *(const bf16x8*)(wt1b + (w*16 + lr) * 64 + ks*32 + lg * 8);
#pragma unroll
      for (int mt = 0; mt < 4; mt++) {
        bf16x8 af = *(const bf16x8*)(sB + (mt*16 + lr) * 72 + ks*32 + lg * 8);
        acc[mt] = __builtin_amdgcn_mfma_f32_16x16x32_bf16(af, bf, acc[mt], 0, 0, 0);
      }
    }
    float bias = b1b[w*16 + lr];
#pragma unroll
    for (int mt = 0; mt < 4; mt++)
#pragma unroll
      for (int r = 0; r < 4; r++)
        sC[(mt*16 + lg*4 + r) * 72 + w*16 + lr] = f2bs(fmaxf(acc[mt][r] + bias, 0.f));
  }
  __syncthreads();

  // layer C: K=64, N=128, segmax via acc-init mask
  {
    f32x4 acc[4][2];
#pragma unroll
    for (int mt = 0; mt < 4; mt++) {
      f32x4 vi;
#pragma unroll
      for (int r = 0; r < 4; r++) vi[r] = sval[mt*16 + lg*4 + r] ? 0.f : -1e30f;
      acc[mt][0] = vi; acc[mt][1] = vi;
    }
#pragma unroll
    for (int ks = 0; ks < 2; ks++) {
      bf16x8 bf0 = *(const bf16x8*)(wt1c + (w*32 + lr)      * 64 + ks*32 + lg * 8);
      bf16x8 bf1 = *(const bf16x8*)(wt1c + (w*32 + 16 + lr) * 64 + ks*32 + lg * 8);
#pragma unroll
      for (int mt = 0; mt < 4; mt++) {
        bf16x8 af = *(const bf16x8*)(sC + (mt*16 + lr) * 72 + ks*32 + lg * 8);
        acc[mt][0] = __builtin_amdgcn_mfma_f32_16x16x32_bf16(af, bf0, acc[mt][0], 0, 0, 0);
        acc[mt][1] = __builtin_amdgcn_mfma_f32_16x16x32_bf16(af, bf1, acc[mt][1], 0, 0, 0);
      }
    }
#pragma unroll
    for (int nt = 0; nt < 2; nt++) {
      float m = -3e38f;
#pragma unroll
      for (int mt = 0; mt < 4; mt++)
#pragma unroll
        for (int r = 0; r < 4; r++) m = fmaxf(m, acc[mt][nt][r]);
      m = fmaxf(m, __shfl_xor(m, 16, 64));
      m = fmaxf(m, __shfl_xor(m, 32, 64));
      if (lg == 0) {
        int ch = w*32 + nt*16 + lr;
        x1b[seg*128 + ch] = f2bs(fmaxf(m + b1c[ch], 0.f));
      }
    }
  }
}

// ---------------- K2: conv2 MFMA ([x1(128),rel(3)] pad160 -> 128 -> 128 -> 256, segmax) ----
// Writes xg[2048][288] bf16 (cols 0..255) for the g-MLP GEMM chain.
__global__ __launch_bounds__(256) void k_conv2(
    const float* __restrict__ pos1, const float* __restrict__ pos2,
    const int* __restrict__ esrc, const short* __restrict__ x1b,
    const short* __restrict__ wt2a, const float* __restrict__ b2a,
    const short* __restrict__ wt2b, const float* __restrict__ b2b,
    const short* __restrict__ wt2c, const float* __restrict__ b2c,
    short* __restrict__ xg) {
  __shared__ __align__(16) short sX[64 * 168];
  __shared__ __align__(16) short sY[64 * 136];
  __shared__ short sval[64];

  int seg = blockIdx.x, tid = threadIdx.x;
  int lane = tid & 63;
  int w  = tid >> 6;
  int lr = lane & 15;
  int lg = lane >> 4;

  {
    int e = tid >> 2, q = tid & 3;
    int s = esrc[seg*64 + e];
    const uint4* src = (const uint4*)(x1b + s * 128) + q * 4;
    uint4* dst = (uint4*)(sX + e * 168 + q * 32);
#pragma unroll
    for (int i = 0; i < 4; i++) dst[i] = src[i];
  }
  if (tid < 64) {
    int e = seg * 64 + tid;
    int s = esrc[e];
    sval[tid] = (short)((tid == 0) || (s > esrc[e - 1]));
    short* row = sX + tid * 168;
    row[128] = f2bs(pos1[s*3+0] - pos2[seg*3+0]);
    row[129] = f2bs(pos1[s*3+1] - pos2[seg*3+1]);
    row[130] = f2bs(pos1[s*3+2] - pos2[seg*3+2]);
#pragma unroll
    for (int i = 131; i < 168; i++) row[i] = 0;
  }
  __syncthreads();

  // layer A: K=160
  {
    f32x4 acc[4][2];
#pragma unroll
    for (int mt = 0; mt < 4; mt++) { acc[mt][0] = (f32x4){0.f,0.f,0.f,0.f}; acc[mt][1] = (f32x4){0.f,0.f,0.f,0.f}; }
#pragma unroll
    for (int ks = 0; ks < 5; ks++) {
      bf16x8 bf0 = *(const bf16x8*)(wt2a + (w*32 + lr)      * 160 + ks*32 + lg * 8);
      bf16x8 bf1 = *(const bf16x8*)(wt2a + (w*32 + 16 + lr) * 160 + ks*32 + lg * 8);
#pragma unroll
      for (int mt = 0; mt < 4; mt++) {
        bf16x8 af = *(const bf16x8*)(sX + (mt*16 + lr) * 168 + ks*32 + lg * 8);
        acc[mt][0] = __builtin_amdgcn_mfma_f32_16x16x32_bf16(af, bf0, acc[mt][0], 0, 0, 0);
        acc[mt][1] = __builtin_amdgcn_mfma_f32_16x16x32_bf16(af, bf1, acc[mt][1], 0, 0, 0);
      }
    }
    float bias0 = b2a[w*32 + lr], bias1 = b2a[w*32 + 16 + lr];
#pragma unroll
    for (int mt = 0; mt < 4; mt++)
#pragma unroll
      for (int r = 0; r < 4; r++) {
        int row = mt*16 + lg*4 + r;
        sY[row * 136 + w*32 + lr]      = f2bs(fmaxf(acc[mt][0][r] + bias0, 0.f));
        sY[row * 136 + w*32 + 16 + lr] = f2bs(fmaxf(acc[mt][1][r] + bias1, 0.f));
      }
  }
  __syncthreads();

  // layer B: K=128
  {
    f32x4 acc[4][2];
#pragma unroll
    for (int mt = 0; mt < 4; mt++) { acc[mt][0] = (f32x4){0.f,0.f,0.f,0.f}; acc[mt][1] = (f32x4){0.f,0.f,0.f,0.f}; }
#pragma unroll
    for (int ks = 0; ks < 4; ks++) {
      bf16x8 bf0 = *(const bf16x8*)(wt2b + (w*32 + lr)      * 128 + ks*32 + lg * 8);
      bf16x8 bf1 = *(const bf16x8*)(wt2b + (w*32 + 16 + lr) * 128 + ks*32 + lg * 8);
#pragma unroll
      for (int mt = 0; mt < 4; mt++) {
        bf16x8 af = *(const bf16x8*)(sY + (mt*16 + lr) * 136 + ks*32 + lg * 8);
        acc[mt][0] = __builtin_amdgcn_mfma_f32_16x16x32_bf16(af, bf0, acc[mt][0], 0, 0, 0);
        acc[mt][1] = __builtin_amdgcn_mfma_f32_16x16x32_bf16(af, bf1, acc[mt][1], 0, 0, 0);
      }
    }
    float bias0 = b2b[w*32 + lr], bias1 = b2b[w*32 + 16 + lr];
#pragma unroll
    for (int mt = 0; mt < 4; mt++)
#pragma unroll
      for (int r = 0; r < 4; r++) {
        int row = mt*16 + lg*4 + r;
        sX[row * 136 + w*32 + lr]      = f2bs(fmaxf(acc[mt][0][r] + bias0, 0.f));
        sX[row * 136 + w*32 + 16 + lr] = f2bs(fmaxf(acc[mt][1][r] + bias1, 0.f));
      }
  }
  __syncthreads();

  // layer C: K=128, N=256, segmax via acc-init mask -> xg cols
  {
    f32x4 acc[4][4];
#pragma unroll
    for (int mt = 0; mt < 4; mt++) {
      f32x4 vi;
#pragma unroll
      for (int r = 0; r < 4; r++) vi[r] = sval[mt*16 + lg*4 + r] ? 0.f : -1e30f;
#pragma unroll
      for (int nt = 0; nt < 4; nt++) acc[mt][nt] = vi;
    }
#pragma unroll
    for (int ks = 0; ks < 4; ks++) {
      bf16x8 bfr[4];
#pragma unroll
      for (int nt = 0; nt < 4; nt++)
        bfr[nt] = *(const bf16x8*)(wt2c + (w*64 + nt*16 + lr) * 128 + ks*32 + lg * 8);
#pragma unroll
      for (int mt = 0; mt < 4; mt++) {
        bf16x8 af = *(const bf16x8*)(sX + (mt*16 + lr) * 136 + ks*32 + lg * 8);
#pragma unroll
        for (int nt = 0; nt < 4; nt++)
          acc[mt][nt] = __builtin_amdgcn_mfma_f32_16x16x32_bf16(af, bfr[nt], acc[mt][nt], 0, 0, 0);
      }
    }
#pragma unroll
    for (int nt = 0; nt < 4; nt++) {
      float m = -3e38f;
#pragma unroll
      for (int mt = 0; mt < 4; mt++)
#pragma unroll
        for (int r = 0; r < 4; r++) m = fmaxf(m, acc[mt][nt][r]);
      m = fmaxf(m, __shfl_xor(m, 16, 64));
      m = fmaxf(m, __shfl_xor(m, 32, 64));
      if (lg == 0) {
        int ch = w*64 + nt*16 + lr;
        xg[seg*288 + ch] = f2bs(fmaxf(m + b2c[ch], 0.f));
      }
    }
  }
}

// ---------------- K3: generic MFMA GEMM for the g-MLP chain ----------------
// A[2048][KP] bf16 row-major, Bt[N][KP] bf16, out = relu(A@B + bias) (bf16) or
// column-max over the block's 64 rows + bias -> gpart[32][1024] (POOL).
// Block tile: M=64 x N=256 (4 waves x 64ch); grid = 32 * (N/256), mb = bid&31.
template<int KP, bool RELU, bool POOL>
__global__ __launch_bounds__(256) void k_gemm(
    const short* __restrict__ A, const short* __restrict__ Bt,
    const float* __restrict__ bias, short* __restrict__ outB,
    float* __restrict__ outP, int N) {
  constexpr int CHUNK = (KP > 288) ? 256 : KP;
  constexpr int NCH   = KP / CHUNK;
  constexpr int LS    = CHUNK + 8;   // stride: (LS*2/4) mod 32 = 4 or 20 -> conflict-free
  constexpr int CQ    = CHUNK / 4;
  __shared__ __align__(16) short sA[64 * LS];

  int bid = blockIdx.x;
  int mb = bid & 31, nb = bid >> 5;
  int tid = threadIdx.x;
  int lane = tid & 63, w = tid >> 6;
  int lr = lane & 15, lg = lane >> 4;
  int n0 = nb * 256 + w * 64;

  f32x4 acc[4][4];
#pragma unroll
  for (int mt = 0; mt < 4; mt++)
#pragma unroll
    for (int nt = 0; nt < 4; nt++) acc[mt][nt] = (f32x4){0.f, 0.f, 0.f, 0.f};

#pragma unroll
  for (int kc = 0; kc < NCH; kc++) {
    if (kc) __syncthreads();
    {
      int r = tid >> 2, q = tid & 3;
      const uint4* src = (const uint4*)(A + (mb*64 + r) * KP + kc*CHUNK + q*CQ);
      uint4* dst = (uint4*)(sA + r * LS + q * CQ);
#pragma unroll
      for (int i = 0; i < CQ/8; i++) dst[i] = src[i];
    }
    __syncthreads();
#pragma unroll
    for (int ks = 0; ks < CHUNK/32; ks++) {
      bf16x8 bf[4];
#pragma unroll
      for (int nt = 0; nt < 4; nt++)
        bf[nt] = *(const bf16x8*)(Bt + (n0 + nt*16 + lr) * KP + kc*CHUNK + ks*32 + lg*8);
#pragma unroll
      for (int mt = 0; mt < 4; mt++) {
        bf16x8 af = *(const bf16x8*)(sA + (mt*16 + lr) * LS + ks*32 + lg*8);
#pragma unroll
        for (int nt = 0; nt < 4; nt++)
          acc[mt][nt] = __builtin_amdgcn_mfma_f32_16x16x32_bf16(af, bf[nt], acc[mt][nt], 0, 0, 0);
      }
    }
  }

  if constexpr (POOL) {
#pragma unroll
    for (int nt = 0; nt < 4; nt++) {
      float m = -3e38f;
#pragma unroll
      for (int mt = 0; mt < 4; mt++)
#pragma unroll
        for (int rr = 0; rr < 4; rr++) m = fmaxf(m, acc[mt][nt][rr]);
      m = fmaxf(m, __shfl_xor(m, 16, 64));
      m = fmaxf(m, __shfl_xor(m, 32, 64));
      if (lg == 0) {
        int col = n0 + nt*16 + lr;
        outP[mb * 1024 + col] = m + bias[col];
      }
    }
  } else {
#pragma unroll
    for (int nt = 0; nt < 4; nt++) {
      int col = n0 + nt*16 + lr;
      float bv = bias[col];
#pragma unroll
      for (int mt = 0; mt < 4; mt++)
#pragma unroll
        for (int rr = 0; rr < 4; rr++) {
          int row = mb*64 + mt*16 + lg*4 + rr;
          float v = acc[mt][nt][rr] + bv;
          if (RELU) v = fmaxf(v, 0.f);
          outB[row * N + col] = f2bs(v);
        }
    }
  }
}

// ---------------- K4: reduce 2 partials per batch -> g[16][1024] ----------------
__global__ __launch_bounds__(256) void k_pool(const float* __restrict__ gpart,
                                              float* __restrict__ g) {
  int gid = blockIdx.x * 256 + threadIdx.x;  // 16384
  int b = gid >> 10, ch = gid & 1023;
  g[gid] = fmaxf(gpart[(b*2) * 1024 + ch], gpart[(b*2 + 1) * 1024 + ch]);
}

// ---------------- head layers ----------------
__global__ __launch_bounds__(256) void k_l1(const float* __restrict__ g,
                                            const float* __restrict__ w,
                                            const float* __restrict__ bias,
                                            float* __restrict__ out) {
  int gid = blockIdx.x * 256 + threadIdx.x;  // 8192
  int b = gid >> 9, j = gid & 511;
  const float* gr = g + b * 1024;
  float acc = bias[j];
  for (int k = 0; k < 1024; k++) acc += gr[k] * w[k * 512 + j];
  out[gid] = fmaxf(acc, 0.f);
}

__global__ __launch_bounds__(256) void k_l2(const float* __restrict__ h,
                                            const float* __restrict__ w,
                                            const float* __restrict__ bias,
                                            float* __restrict__ out) {
  int gid = blockIdx.x * 256 + threadIdx.x;  // 4096
  int b = gid >> 8, j = gid & 255;
  const float* hr = h + b * 512;
  float acc = bias[j];
  for (int k = 0; k < 512; k++) acc += hr[k] * w[k * 256 + j];
  out[gid] = fmaxf(acc, 0.f);
}

__global__ __launch_bounds__(256) void k_l3(const float* __restrict__ h,
                                            const float* __restrict__ w,
                                            const float* __restrict__ bias,
                                            float* __restrict__ out) {
  __shared__ float sl[160];
  int tid = threadIdx.x;
  if (tid < 160) {
    int b = tid / 10, j = tid - b * 10;
    const float* hr = h + b * 256;
    float acc = bias[j];
    for (int k = 0; k < 256; k++) acc += hr[k] * w[k * 10 + j];
    sl[tid] = acc;
  }
  __syncthreads();
  if (tid < 16) {
    float m = -INFINITY;
#pragma unroll
    for (int j = 0; j < 10; j++) m = fmaxf(m, sl[tid * 10 + j]);
    float s = 0.f;
#pragma unroll
    for (int j = 0; j < 10; j++) s += expf(sl[tid * 10 + j] - m);
    float lse = m + logf(s);
#pragma unroll
    for (int j = 0; j < 10; j++) out[tid * 10 + j] = sl[tid * 10 + j] - lse;
  }
}

extern "C" void kernel_launch(void* const* d_in, const int* in_sizes, int n_in,
                              void* d_out, int out_size, void* d_ws, size_t ws_size,
                              hipStream_t stream) {
  (void)in_sizes; (void)n_in; (void)out_size; (void)ws_size;
  const float* pos    = (const float*)d_in[0];
  const int*   idx1   = (const int*)d_in[1];
  const int*   e1_src = (const int*)d_in[2];
  const int*   idx2   = (const int*)d_in[5];
  const int*   e2_src = (const int*)d_in[6];
  const float* w1a = (const float*)d_in[9],  *b1a = (const float*)d_in[10];
  const float* w1b = (const float*)d_in[11], *b1b = (const float*)d_in[12];
  const float* w1c = (const float*)d_in[13], *b1c = (const float*)d_in[14];
  const float* w2a = (const float*)d_in[15], *b2a = (const float*)d_in[16];
  const float* w2b = (const float*)d_in[17], *b2b = (const float*)d_in[18];
  const float* w2c = (const float*)d_in[19], *b2c = (const float*)d_in[20];
  const float* g1w = (const float*)d_in[21], *g1b = (const float*)d_in[22];
  const float* g2w = (const float*)d_in[23], *g2b = (const float*)d_in[24];
  const float* g3w = (const float*)d_in[25], *g3b = (const float*)d_in[26];
  const float* l1w = (const float*)d_in[27], *l1b = (const float*)d_in[28];
  const float* l2w = (const float*)d_in[29], *l2b = (const float*)d_in[30];
  const float* l3w = (const float*)d_in[31], *l3b = (const float*)d_in[32];

  float* ws    = (float*)d_ws;
  float* pos1  = ws + POS1_OFF;
  float* pos2  = ws + POS2_OFF;
  float* gpart = ws + GPART_OFF;
  float* g     = ws + G_OFF;
  float* h1h   = ws + H1H_OFF;
  float* h2h   = ws + H2H_OFF;
  short* sbase = (short*)(ws + FLT_END);
  short* x1b   = sbase + X1B_OFF;
  short* xg    = sbase + XG_OFF;
  short* h1    = sbase + H1_OFF;
  short* h2    = sbase + H2_OFF;
  short* wt1a  = sbase + WT1A_OFF;
  short* wt1b  = sbase + WT1B_OFF;
  short* wt1c  = sbase + WT1C_OFF;
  short* wt2a  = sbase + WT2A_OFF;
  short* wt2b  = sbase + WT2B_OFF;
  short* wt2c  = sbase + WT2C_OFF;
  short* gt1   = sbase + GT1_OFF;
  short* gt2   = sbase + GT2_OFF;
  short* gt3   = sbase + GT3_OFF;

  k_prep<<<3177, 256, 0, stream>>>(w1a, w1b, w1c, w2a, w2b, w2c, g1w, g2w, g3w,
                                   wt1a, wt1b, wt1c, wt2a, wt2b, wt2c, gt1, gt2, gt3);
  k_gather<<<(N1 + N2 + 255) / 256, 256, 0, stream>>>(pos, idx1, idx2, pos1, pos2, xg);
  k_conv1<<<N1, 256, 0, stream>>>(pos, pos1, e1_src, wt1a, b1a, wt1b, b1b, wt1c, b1c, x1b);
  k_conv2<<<N2, 256, 0, stream>>>(pos1, pos2, e2_src, x1b, wt2a, b2a, wt2b, b2b, wt2c, b2c, xg);
  k_gemm<288, true,  false><<<32,  256, 0, stream>>>(xg, gt1, g1b, h1, nullptr, 256);
  k_gemm<256, true,  false><<<64,  256, 0, stream>>>(h1, gt2, g2b, h2, nullptr, 512);
  k_gemm<512, false, true ><<<128, 256, 0, stream>>>(h2, gt3, g3b, nullptr, gpart, 1024);
  k_pool<<<64, 256, 0, stream>>>(gpart, g);
  k_l1<<<32, 256, 0, stream>>>(g, l1w, l1b, h1h);
  k_l2<<<16, 256, 0, stream>>>(h1h, l2w, l2b, h2h);
  k_l3<<<1, 256, 0, stream>>>(h2h, l3w, l3b, (float*)d_out);
}

// Round 10
// 299.256 us; speedup vs baseline: 2.5193x; 1.0075x over previous
//
#include <hip/hip_runtime.h>
#include <hip/hip_bf16.h>
#include <math.h>

#define NBATCH 16
#define S1     512
#define S2     128
#define MAXN   64
#define N1     8192   /* NBATCH*S1 */
#define N2     2048   /* NBATCH*S2 */

// ---------------- workspace layout ----------------
// float region (offsets in floats):
#define POS1_OFF  0           /* 8192*3  = 24576 */
#define POS2_OFF  24576       /* 2048*3  = 6144  */
#define GPART_OFF 30720       /* 32*1024 = 32768 */
#define G_OFF     63488       /* 16*1024 = 16384 */
#define H1H_OFF   79872       /* 16*512  = 8192  */
#define H2H_OFF   88064       /* 16*256  = 4096  */
#define FLT_END   92160
// bf16(short) region, base = (short*)(ws + FLT_END), offsets in shorts:
#define X1B_OFF   0           /* 8192*128  = 1048576 */
#define XG_OFF    1048576     /* 2048*288  = 589824  */
#define H1_OFF    1638400     /* 2048*256  = 524288  */
#define H2_OFF    2162688     /* 2048*512  = 1048576 */
#define WT1A_OFF  3211264     /* [64][32]   = 2048  */
#define WT1B_OFF  3213312     /* [64][64]   = 4096  */
#define WT1C_OFF  3217408     /* [128][64]  = 8192  */
#define WT2A_OFF  3225600     /* [128][160] = 20480 */
#define WT2B_OFF  3246080     /* [128][128] = 16384 */
#define WT2C_OFF  3262464     /* [256][128] = 32768 */
#define GT1_OFF   3295232     /* [256][288] = 73728  */
#define GT2_OFF   3368960     /* [512][256] = 131072 */
#define GT3_OFF   3500032     /* [1024][512]= 524288 */

typedef __attribute__((ext_vector_type(8))) short bf16x8;
typedef __attribute__((ext_vector_type(4))) float f32x4;

static __device__ __forceinline__ short f2bs(float f) {
  __hip_bfloat16 b = __float2bfloat16(f);
  return __builtin_bit_cast(short, b);
}

// ---------------- K_prep: LDS-tiled transpose, fp32[K][N] -> bf16[N][KP] ----------------
// 32x32 tiles, coalesced reads (consecutive n) and writes (consecutive k).
__global__ __launch_bounds__(256) void k_prep(
    const float* __restrict__ w1a, const float* __restrict__ w1b, const float* __restrict__ w1c,
    const float* __restrict__ w2a, const float* __restrict__ w2b, const float* __restrict__ w2c,
    const float* __restrict__ g1w, const float* __restrict__ g2w, const float* __restrict__ g3w,
    short* __restrict__ wt1a, short* __restrict__ wt1b, short* __restrict__ wt1c,
    short* __restrict__ wt2a, short* __restrict__ wt2b, short* __restrict__ wt2c,
    short* __restrict__ gt1,  short* __restrict__ gt2,  short* __restrict__ gt3) {
  __shared__ float tile[32][33];
  int t = blockIdx.x;
  const float* src; short* dst; int K, N, KP, tilesN, base;
  if      (t < 2)   { src=w1a; dst=wt1a; K=3;   N=64;   KP=32;  tilesN=2;  base=0; }
  else if (t < 6)   { src=w1b; dst=wt1b; K=64;  N=64;   KP=64;  tilesN=2;  base=2; }
  else if (t < 14)  { src=w1c; dst=wt1c; K=64;  N=128;  KP=64;  tilesN=4;  base=6; }
  else if (t < 34)  { src=w2a; dst=wt2a; K=131; N=128;  KP=160; tilesN=4;  base=14; }
  else if (t < 50)  { src=w2b; dst=wt2b; K=128; N=128;  KP=128; tilesN=4;  base=34; }
  else if (t < 82)  { src=w2c; dst=wt2c; K=128; N=256;  KP=128; tilesN=8;  base=50; }
  else if (t < 154) { src=g1w; dst=gt1;  K=259; N=256;  KP=288; tilesN=8;  base=82; }
  else if (t < 282) { src=g2w; dst=gt2;  K=256; N=512;  KP=256; tilesN=16; base=154; }
  else              { src=g3w; dst=gt3;  K=512; N=1024; KP=512; tilesN=32; base=282; }
  int idx = t - base;
  int tk = idx / tilesN, tn = idx - tk * tilesN;
  int k0 = tk * 32, n0 = tn * 32;
  int tx = threadIdx.x & 31, ty = threadIdx.x >> 5;
#pragma unroll
  for (int i = 0; i < 4; i++) {
    int k = k0 + ty + i * 8;
    tile[ty + i * 8][tx] = (k < K) ? src[k * N + n0 + tx] : 0.f;
  }
  __syncthreads();
#pragma unroll
  for (int i = 0; i < 4; i++) {
    int n = n0 + ty + i * 8;
    dst[n * KP + k0 + tx] = f2bs(tile[tx][ty + i * 8]);
  }
}

// ---------------- K0: gather pos1/pos2 + xg pos columns & pad ----------------
__global__ __launch_bounds__(256) void k_gather(const float* __restrict__ pos,
                                                const int* __restrict__ idx1,
                                                const int* __restrict__ idx2,
                                                float* __restrict__ pos1,
                                                float* __restrict__ pos2,
                                                short* __restrict__ xg) {
  int i = blockIdx.x * 256 + threadIdx.x;
  if (i < N1) {
    int s = idx1[i];
    pos1[i*3+0] = pos[s*3+0]; pos1[i*3+1] = pos[s*3+1]; pos1[i*3+2] = pos[s*3+2];
  } else if (i < N1 + N2) {
    int j = i - N1;
    int s = idx1[idx2[j]];
    float p0 = pos[s*3+0], p1 = pos[s*3+1], p2 = pos[s*3+2];
    pos2[j*3+0] = p0; pos2[j*3+1] = p1; pos2[j*3+2] = p2;
    short* row = xg + j * 288;
    row[256] = f2bs(p0); row[257] = f2bs(p1); row[258] = f2bs(p2);
#pragma unroll
    for (int c = 259; c < 288; c++) row[c] = 0;
  }
}

// ---------------- K1: conv1 MFMA (rel(3,pad32) -> 64 -> 64 -> 128, segmax) ----------------
__global__ __launch_bounds__(256) void k_conv1(
    const float* __restrict__ pos, const float* __restrict__ pos1,
    const int* __restrict__ esrc,
    const short* __restrict__ wt1a, const float* __restrict__ b1a,
    const short* __restrict__ wt1b, const float* __restrict__ b1b,
    const short* __restrict__ wt1c, const float* __restrict__ b1c,
    short* __restrict__ x1b) {
  __shared__ __align__(16) short sA[64 * 40];
  __shared__ __align__(16) short sB[64 * 72];
  __shared__ __align__(16) short sC[64 * 72];
  __shared__ short sval[64];

  int seg = blockIdx.x, tid = threadIdx.x;
  int lane = tid & 63;
  int w  = tid >> 6;
  int lr = lane & 15;
  int lg = lane >> 4;

  if (tid < 64) {
    int e = seg * 64 + tid;
    int s = esrc[e];
    sval[tid] = (short)((tid == 0) || (s > esrc[e - 1]));
    short* row = sA + tid * 40;
    row[0] = f2bs(pos[s*3+0] - pos1[seg*3+0]);
    row[1] = f2bs(pos[s*3+1] - pos1[seg*3+1]);
    row[2] = f2bs(pos[s*3+2] - pos1[seg*3+2]);
#pragma unroll
    for (int i = 3; i < 40; i++) row[i] = 0;
  }
  __syncthreads();

  // layer A: K=32, wave w -> ch [w*16,+16)
  {
    f32x4 acc[4];
#pragma unroll
    for (int mt = 0; mt < 4; mt++) acc[mt] = (f32x4){0.f, 0.f, 0.f, 0.f};
    bf16x8 bf = *(const bf16x8*)(wt1a + (w*16 + lr) * 32 + lg * 8);
#pragma unroll
    for (int mt = 0; mt < 4; mt++) {
      bf16x8 af = *(const bf16x8*)(sA + (mt*16 + lr) * 40 + lg * 8);
      acc[mt] = __builtin_amdgcn_mfma_f32_16x16x32_bf16(af, bf, acc[mt], 0, 0, 0);
    }
    float bias = b1a[w*16 + lr];
#pragma unroll
    for (int mt = 0; mt < 4; mt++)
#pragma unroll
      for (int r = 0; r < 4; r++)
        sB[(mt*16 + lg*4 + r) * 72 + w*16 + lr] = f2bs(fmaxf(acc[mt][r] + bias, 0.f));
  }
  __syncthreads();

  // layer B: K=64
  {
    f32x4 acc[4];
#pragma unroll
    for (int mt = 0; mt < 4; mt++) acc[mt] = (f32x4){0.f, 0.f, 0.f, 0.f};
#pragma unroll
    for (int ks = 0; ks < 2; ks++) {
      bf16x8 bf = *(const bf16x8*)(wt1b + (w*16 + lr) * 64 + ks*32 + lg * 8);
#pragma unroll
      for (int mt = 0; mt < 4; mt++) {
        bf16x8 af = *(const bf16x8*)(sB + (mt*16 + lr) * 72 + ks*32 + lg * 8);
        acc[mt] = __builtin_amdgcn_mfma_f32_16x16x32_bf16(af, bf, acc[mt], 0, 0, 0);
      }
    }
    float bias = b1b[w*16 + lr];
#pragma unroll
    for (int mt = 0; mt < 4; mt++)
#pragma unroll
      for (int r = 0; r < 4; r++)
        sC[(mt*16 + lg*4 + r) * 72 + w*16 + lr] = f2bs(fmaxf(acc[mt][r] + bias, 0.f));
  }
  __syncthreads();

  // layer C: K=64, N=128, segmax via acc-init mask
  {
    f32x4 acc[4][2];
#pragma unroll
    for (int mt = 0; mt < 4; mt++) {
      f32x4 vi;
#pragma unroll
      for (int r = 0; r < 4; r++) vi[r] = sval[mt*16 + lg*4 + r] ? 0.f : -1e30f;
      acc[mt][0] = vi; acc[mt][1] = vi;
    }
#pragma unroll
    for (int ks = 0; ks < 2; ks++) {
      bf16x8 bf0 = *(const bf16x8*)(wt1c + (w*32 + lr)      * 64 + ks*32 + lg * 8);
      bf16x8 bf1 = *(const bf16x8*)(wt1c + (w*32 + 16 + lr) * 64 + ks*32 + lg * 8);
#pragma unroll
      for (int mt = 0; mt < 4; mt++) {
        bf16x8 af = *(const bf16x8*)(sC + (mt*16 + lr) * 72 + ks*32 + lg * 8);
        acc[mt][0] = __builtin_amdgcn_mfma_f32_16x16x32_bf16(af, bf0, acc[mt][0], 0, 0, 0);
        acc[mt][1] = __builtin_amdgcn_mfma_f32_16x16x32_bf16(af, bf1, acc[mt][1], 0, 0, 0);
      }
    }
#pragma unroll
    for (int nt = 0; nt < 2; nt++) {
      float m = -3e38f;
#pragma unroll
      for (int mt = 0; mt < 4; mt++)
#pragma unroll
        for (int r = 0; r < 4; r++) m = fmaxf(m, acc[mt][nt][r]);
      m = fmaxf(m, __shfl_xor(m, 16, 64));
      m = fmaxf(m, __shfl_xor(m, 32, 64));
      if (lg == 0) {
        int ch = w*32 + nt*16 + lr;
        x1b[seg*128 + ch] = f2bs(fmaxf(m + b1c[ch], 0.f));
      }
    }
  }
}

// ---------------- K2: conv2 MFMA ([x1(128),rel(3)] pad160 -> 128 -> 128 -> 256, segmax) ----
// Writes xg[2048][288] bf16 (cols 0..255) for the g-MLP GEMM chain.
__global__ __launch_bounds__(256) void k_conv2(
    const float* __restrict__ pos1, const float* __restrict__ pos2,
    const int* __restrict__ esrc, const short* __restrict__ x1b,
    const short* __restrict__ wt2a, const float* __restrict__ b2a,
    const short* __restrict__ wt2b, const float* __restrict__ b2b,
    const short* __restrict__ wt2c, const float* __restrict__ b2c,
    short* __restrict__ xg) {
  __shared__ __align__(16) short sX[64 * 168];
  __shared__ __align__(16) short sY[64 * 136];
  __shared__ short sval[64];

  int seg = blockIdx.x, tid = threadIdx.x;
  int lane = tid & 63;
  int w  = tid >> 6;
  int lr = lane & 15;
  int lg = lane >> 4;

  {
    int e = tid >> 2, q = tid & 3;
    int s = esrc[seg*64 + e];
    const uint4* src = (const uint4*)(x1b + s * 128) + q * 4;
    uint4* dst = (uint4*)(sX + e * 168 + q * 32);
#pragma unroll
    for (int i = 0; i < 4; i++) dst[i] = src[i];
  }
  if (tid < 64) {
    int e = seg * 64 + tid;
    int s = esrc[e];
    sval[tid] = (short)((tid == 0) || (s > esrc[e - 1]));
    short* row = sX + tid * 168;
    row[128] = f2bs(pos1[s*3+0] - pos2[seg*3+0]);
    row[129] = f2bs(pos1[s*3+1] - pos2[seg*3+1]);
    row[130] = f2bs(pos1[s*3+2] - pos2[seg*3+2]);
#pragma unroll
    for (int i = 131; i < 168; i++) row[i] = 0;
  }
  __syncthreads();

  // layer A: K=160
  {
    f32x4 acc[4][2];
#pragma unroll
    for (int mt = 0; mt < 4; mt++) { acc[mt][0] = (f32x4){0.f,0.f,0.f,0.f}; acc[mt][1] = (f32x4){0.f,0.f,0.f,0.f}; }
#pragma unroll
    for (int ks = 0; ks < 5; ks++) {
      bf16x8 bf0 = *(const bf16x8*)(wt2a + (w*32 + lr)      * 160 + ks*32 + lg * 8);
      bf16x8 bf1 = *(const bf16x8*)(wt2a + (w*32 + 16 + lr) * 160 + ks*32 + lg * 8);
#pragma unroll
      for (int mt = 0; mt < 4; mt++) {
        bf16x8 af = *(const bf16x8*)(sX + (mt*16 + lr) * 168 + ks*32 + lg * 8);
        acc[mt][0] = __builtin_amdgcn_mfma_f32_16x16x32_bf16(af, bf0, acc[mt][0], 0, 0, 0);
        acc[mt][1] = __builtin_amdgcn_mfma_f32_16x16x32_bf16(af, bf1, acc[mt][1], 0, 0, 0);
      }
    }
    float bias0 = b2a[w*32 + lr], bias1 = b2a[w*32 + 16 + lr];
#pragma unroll
    for (int mt = 0; mt < 4; mt++)
#pragma unroll
      for (int r = 0; r < 4; r++) {
        int row = mt*16 + lg*4 + r;
        sY[row * 136 + w*32 + lr]      = f2bs(fmaxf(acc[mt][0][r] + bias0, 0.f));
        sY[row * 136 + w*32 + 16 + lr] = f2bs(fmaxf(acc[mt][1][r] + bias1, 0.f));
      }
  }
  __syncthreads();

  // layer B: K=128
  {
    f32x4 acc[4][2];
#pragma unroll
    for (int mt = 0; mt < 4; mt++) { acc[mt][0] = (f32x4){0.f,0.f,0.f,0.f}; acc[mt][1] = (f32x4){0.f,0.f,0.f,0.f}; }
#pragma unroll
    for (int ks = 0; ks < 4; ks++) {
      bf16x8 bf0 = *(const bf16x8*)(wt2b + (w*32 + lr)      * 128 + ks*32 + lg * 8);
      bf16x8 bf1 = *(const bf16x8*)(wt2b + (w*32 + 16 + lr) * 128 + ks*32 + lg * 8);
#pragma unroll
      for (int mt = 0; mt < 4; mt++) {
        bf16x8 af = *(const bf16x8*)(sY + (mt*16 + lr) * 136 + ks*32 + lg * 8);
        acc[mt][0] = __builtin_amdgcn_mfma_f32_16x16x32_bf16(af, bf0, acc[mt][0], 0, 0, 0);
        acc[mt][1] = __builtin_amdgcn_mfma_f32_16x16x32_bf16(af, bf1, acc[mt][1], 0, 0, 0);
      }
    }
    float bias0 = b2b[w*32 + lr], bias1 = b2b[w*32 + 16 + lr];
    __syncthreads();
#pragma unroll
    for (int mt = 0; mt < 4; mt++)
#pragma unroll
      for (int r = 0; r < 4; r++) {
        int row = mt*16 + lg*4 + r;
        sX[row * 136 + w*32 + lr]      = f2bs(fmaxf(acc[mt][0][r] + bias0, 0.f));
        sX[row * 136 + w*32 + 16 + lr] = f2bs(fmaxf(acc[mt][1][r] + bias1, 0.f));
      }
  }
  __syncthreads();

  // layer C: K=128, N=256, segmax via acc-init mask -> xg cols
  {
    f32x4 acc[4][4];
#pragma unroll
    for (int mt = 0; mt < 4; mt++) {
      f32x4 vi;
#pragma unroll
      for (int r = 0; r < 4; r++) vi[r] = sval[mt*16 + lg*4 + r] ? 0.f : -1e30f;
#pragma unroll
      for (int nt = 0; nt < 4; nt++) acc[mt][nt] = vi;
    }
#pragma unroll
    for (int ks = 0; ks < 4; ks++) {
      bf16x8 bfr[4];
#pragma unroll
      for (int nt = 0; nt < 4; nt++)
        bfr[nt] = *(const bf16x8*)(wt2c + (w*64 + nt*16 + lr) * 128 + ks*32 + lg * 8);
#pragma unroll
      for (int mt = 0; mt < 4; mt++) {
        bf16x8 af = *(const bf16x8*)(sX + (mt*16 + lr) * 136 + ks*32 + lg * 8);
#pragma unroll
        for (int nt = 0; nt < 4; nt++)
          acc[mt][nt] = __builtin_amdgcn_mfma_f32_16x16x32_bf16(af, bfr[nt], acc[mt][nt], 0, 0, 0);
      }
    }
#pragma unroll
    for (int nt = 0; nt < 4; nt++) {
      float m = -3e38f;
#pragma unroll
      for (int mt = 0; mt < 4; mt++)
#pragma unroll
        for (int r = 0; r < 4; r++) m = fmaxf(m, acc[mt][nt][r]);
      m = fmaxf(m, __shfl_xor(m, 16, 64));
      m = fmaxf(m, __shfl_xor(m, 32, 64));
      if (lg == 0) {
        int ch = w*64 + nt*16 + lr;
        xg[seg*288 + ch] = f2bs(fmaxf(m + b2c[ch], 0.f));
      }
    }
  }
}

// ---------------- K3: generic MFMA GEMM for the g-MLP chain ----------------
// A[2048][KP] bf16 row-major, Bt[N][KP] bf16, out = relu(A@B + bias) (bf16) or
// column-max over the block's 64 rows + bias -> gpart[32][1024] (POOL).
// Block tile: M=64 x N=256 (4 waves x 64ch); grid = 32 * (N/256), mb = bid&31.
template<int KP, bool RELU, bool POOL>
__global__ __launch_bounds__(256) void k_gemm(
    const short* __restrict__ A, const short* __restrict__ Bt,
    const float* __restrict__ bias, short* __restrict__ outB,
    float* __restrict__ outP, int N) {
  constexpr int CHUNK = (KP > 288) ? 256 : KP;
  constexpr int NCH   = KP / CHUNK;
  constexpr int LS    = CHUNK + 8;   // stride: (LS*2/4) mod 32 = 4 or 20 -> conflict-free
  constexpr int CQ    = CHUNK / 4;
  __shared__ __align__(16) short sA[64 * LS];

  int bid = blockIdx.x;
  int mb = bid & 31, nb = bid >> 5;
  int tid = threadIdx.x;
  int lane = tid & 63, w = tid >> 6;
  int lr = lane & 15, lg = lane >> 4;
  int n0 = nb * 256 + w * 64;

  f32x4 acc[4][4];
#pragma unroll
  for (int mt = 0; mt < 4; mt++)
#pragma unroll
    for (int nt = 0; nt < 4; nt++) acc[mt][nt] = (f32x4){0.f, 0.f, 0.f, 0.f};

#pragma unroll
  for (int kc = 0; kc < NCH; kc++) {
    if (kc) __syncthreads();
    {
      int r = tid >> 2, q = tid & 3;
      const uint4* src = (const uint4*)(A + (mb*64 + r) * KP + kc*CHUNK + q*CQ);
      uint4* dst = (uint4*)(sA + r * LS + q * CQ);
#pragma unroll
      for (int i = 0; i < CQ/8; i++) dst[i] = src[i];
    }
    __syncthreads();
#pragma unroll
    for (int ks = 0; ks < CHUNK/32; ks++) {
      bf16x8 bf[4];
#pragma unroll
      for (int nt = 0; nt < 4; nt++)
        bf[nt] = *(const bf16x8*)(Bt + (n0 + nt*16 + lr) * KP + kc*CHUNK + ks*32 + lg*8);
#pragma unroll
      for (int mt = 0; mt < 4; mt++) {
        bf16x8 af = *(const bf16x8*)(sA + (mt*16 + lr) * LS + ks*32 + lg*8);
#pragma unroll
        for (int nt = 0; nt < 4; nt++)
          acc[mt][nt] = __builtin_amdgcn_mfma_f32_16x16x32_bf16(af, bf[nt], acc[mt][nt], 0, 0, 0);
      }
    }
  }

  if constexpr (POOL) {
#pragma unroll
    for (int nt = 0; nt < 4; nt++) {
      float m = -3e38f;
#pragma unroll
      for (int mt = 0; mt < 4; mt++)
#pragma unroll
        for (int rr = 0; rr < 4; rr++) m = fmaxf(m, acc[mt][nt][rr]);
      m = fmaxf(m, __shfl_xor(m, 16, 64));
      m = fmaxf(m, __shfl_xor(m, 32, 64));
      if (lg == 0) {
        int col = n0 + nt*16 + lr;
        outP[mb * 1024 + col] = m + bias[col];
      }
    }
  } else {
#pragma unroll
    for (int nt = 0; nt < 4; nt++) {
      int col = n0 + nt*16 + lr;
      float bv = bias[col];
#pragma unroll
      for (int mt = 0; mt < 4; mt++)
#pragma unroll
        for (int rr = 0; rr < 4; rr++) {
          int row = mb*64 + mt*16 + lg*4 + rr;
          float v = acc[mt][nt][rr] + bv;
          if (RELU) v = fmaxf(v, 0.f);
          outB[row * N + col] = f2bs(v);
        }
    }
  }
}

// ---------------- K4: reduce 2 partials per batch -> g[16][1024] ----------------
__global__ __launch_bounds__(256) void k_pool(const float* __restrict__ gpart,
                                              float* __restrict__ g) {
  int gid = blockIdx.x * 256 + threadIdx.x;  // 16384
  int b = gid >> 10, ch = gid & 1023;
  g[gid] = fmaxf(gpart[(b*2) * 1024 + ch], gpart[(b*2 + 1) * 1024 + ch]);
}

// ---------------- head layers ----------------
__global__ __launch_bounds__(256) void k_l1(const float* __restrict__ g,
                                            const float* __restrict__ w,
                                            const float* __restrict__ bias,
                                            float* __restrict__ out) {
  int gid = blockIdx.x * 256 + threadIdx.x;  // 8192
  int b = gid >> 9, j = gid & 511;
  const float* gr = g + b * 1024;
  float acc = bias[j];
  for (int k = 0; k < 1024; k++) acc += gr[k] * w[k * 512 + j];
  out[gid] = fmaxf(acc, 0.f);
}

__global__ __launch_bounds__(256) void k_l2(const float* __restrict__ h,
                                            const float* __restrict__ w,
                                            const float* __restrict__ bias,
                                            float* __restrict__ out) {
  int gid = blockIdx.x * 256 + threadIdx.x;  // 4096
  int b = gid >> 8, j = gid & 255;
  const float* hr = h + b * 512;
  float acc = bias[j];
  for (int k = 0; k < 512; k++) acc += hr[k] * w[k * 256 + j];
  out[gid] = fmaxf(acc, 0.f);
}

__global__ __launch_bounds__(256) void k_l3(const float* __restrict__ h,
                                            const float* __restrict__ w,
                                            const float* __restrict__ bias,
                                            float* __restrict__ out) {
  __shared__ float sl[160];
  int tid = threadIdx.x;
  if (tid < 160) {
    int b = tid / 10, j = tid - b * 10;
    const float* hr = h + b * 256;
    float acc = bias[j];
    for (int k = 0; k < 256; k++) acc += hr[k] * w[k * 10 + j];
    sl[tid] = acc;
  }
  __syncthreads();
  if (tid < 16) {
    float m = -INFINITY;
#pragma unroll
    for (int j = 0; j < 10; j++) m = fmaxf(m, sl[tid * 10 + j]);
    float s = 0.f;
#pragma unroll
    for (int j = 0; j < 10; j++) s += expf(sl[tid * 10 + j] - m);
    float lse = m + logf(s);
#pragma unroll
    for (int j = 0; j < 10; j++) out[tid * 10 + j] = sl[tid * 10 + j] - lse;
  }
}

extern "C" void kernel_launch(void* const* d_in, const int* in_sizes, int n_in,
                              void* d_out, int out_size, void* d_ws, size_t ws_size,
                              hipStream_t stream) {
  (void)in_sizes; (void)n_in; (void)out_size; (void)ws_size;
  const float* pos    = (const float*)d_in[0];
  const int*   idx1   = (const int*)d_in[1];
  const int*   e1_src = (const int*)d_in[2];
  const int*   idx2   = (const int*)d_in[5];
  const int*   e2_src = (const int*)d_in[6];
  const float* w1a = (const float*)d_in[9],  *b1a = (const float*)d_in[10];
  const float* w1b = (const float*)d_in[11], *b1b = (const float*)d_in[12];
  const float* w1c = (const float*)d_in[13], *b1c = (const float*)d_in[14];
  const float* w2a = (const float*)d_in[15], *b2a = (const float*)d_in[16];
  const float* w2b = (const float*)d_in[17], *b2b = (const float*)d_in[18];
  const float* w2c = (const float*)d_in[19], *b2c = (const float*)d_in[20];
  const float* g1w = (const float*)d_in[21], *g1b = (const float*)d_in[22];
  const float* g2w = (const float*)d_in[23], *g2b = (const float*)d_in[24];
  const float* g3w = (const float*)d_in[25], *g3b = (const float*)d_in[26];
  const float* l1w = (const float*)d_in[27], *l1b = (const float*)d_in[28];
  const float* l2w = (const float*)d_in[29], *l2b = (const float*)d_in[30];
  const float* l3w = (const float*)d_in[31], *l3b = (const float*)d_in[32];

  float* ws    = (float*)d_ws;
  float* pos1  = ws + POS1_OFF;
  float* pos2  = ws + POS2_OFF;
  float* gpart = ws + GPART_OFF;
  float* g     = ws + G_OFF;
  float* h1h   = ws + H1H_OFF;
  float* h2h   = ws + H2H_OFF;
  short* sbase = (short*)(ws + FLT_END);
  short* x1b   = sbase + X1B_OFF;
  short* xg    = sbase + XG_OFF;
  short* h1    = sbase + H1_OFF;
  short* h2    = sbase + H2_OFF;
  short* wt1a  = sbase + WT1A_OFF;
  short* wt1b  = sbase + WT1B_OFF;
  short* wt1c  = sbase + WT1C_OFF;
  short* wt2a  = sbase + WT2A_OFF;
  short* wt2b  = sbase + WT2B_OFF;
  short* wt2c  = sbase + WT2C_OFF;
  short* gt1   = sbase + GT1_OFF;
  short* gt2   = sbase + GT2_OFF;
  short* gt3   = sbase + GT3_OFF;

  k_prep<<<794, 256, 0, stream>>>(w1a, w1b, w1c, w2a, w2b, w2c, g1w, g2w, g3w,
                                  wt1a, wt1b, wt1c, wt2a, wt2b, wt2c, gt1, gt2, gt3);
  k_gather<<<(N1 + N2 + 255) / 256, 256, 0, stream>>>(pos, idx1, idx2, pos1, pos2, xg);
  k_conv1<<<N1, 256, 0, stream>>>(pos, pos1, e1_src, wt1a, b1a, wt1b, b1b, wt1c, b1c, x1b);
  k_conv2<<<N2, 256, 0, stream>>>(pos1, pos2, e2_src, x1b, wt2a, b2a, wt2b, b2b, wt2c, b2c, xg);
  k_gemm<288, true,  false><<<32,  256, 0, stream>>>(xg, gt1, g1b, h1, nullptr, 256);
  k_gemm<256, true,  false><<<64,  256, 0, stream>>>(h1, gt2, g2b, h2, nullptr, 512);
  k_gemm<512, false, true ><<<128, 256, 0, stream>>>(h2, gt3, g3b, nullptr, gpart, 1024);
  k_pool<<<64, 256, 0, stream>>>(gpart, g);
  k_l1<<<32, 256, 0, stream>>>(g, l1w, l1b, h1h);
  k_l2<<<16, 256, 0, stream>>>(h1h, l2w, l2b, h2h);
  k_l3<<<1, 256, 0, stream>>>(h2h, l3w, l3b, (float*)d_out);
}

// Round 13
// 280.744 us; speedup vs baseline: 2.6854x; 1.0659x over previous
//
#include <hip/hip_runtime.h>
#include <hip/hip_bf16.h>
#include <math.h>

#define NBATCH 16
#define S1     512
#define S2     128
#define MAXN   64
#define N1     8192   /* NBATCH*S1 */
#define N2     2048   /* NBATCH*S2 */

// ---------------- workspace layout ----------------
// float region (offsets in floats):
#define POS1_OFF  0           /* 8192*3  = 24576 */
#define POS2_OFF  24576       /* 2048*3  = 6144  */
#define GPART_OFF 30720       /* 32*1024 = 32768 */
#define G_OFF     63488       /* 16*1024 = 16384 */
#define H1H_OFF   79872       /* 16*512  = 8192  */
#define H2H_OFF   88064       /* 16*256  = 4096  */
#define FLT_END   92160
// bf16(short) region, base = (short*)(ws + FLT_END), offsets in shorts:
#define X1B_OFF   0           /* 8192*128  = 1048576 */
#define XG_OFF    1048576     /* 2048*288  = 589824  */
#define H1_OFF    1638400     /* 2048*256  = 524288  */
#define H2_OFF    2162688     /* 2048*512  = 1048576 */
#define WT1A_OFF  3211264     /* [64][32]   = 2048  */
#define WT1B_OFF  3213312     /* [64][64]   = 4096  */
#define WT1C_OFF  3217408     /* [128][64]  = 8192  */
#define WT2A_OFF  3225600     /* [128][160] = 20480 */
#define WT2B_OFF  3246080     /* [128][128] = 16384 */
#define WT2C_OFF  3262464     /* [256][128] = 32768 */
#define GT1_OFF   3295232     /* [256][288] = 73728  */
#define GT2_OFF   3368960     /* [512][256] = 131072 */
#define GT3_OFF   3500032     /* [1024][512]= 524288 */

typedef __attribute__((ext_vector_type(8))) short bf16x8;
typedef __attribute__((ext_vector_type(4))) float f32x4;

static __device__ __forceinline__ short f2bs(float f) {
  __hip_bfloat16 b = __float2bfloat16(f);
  return __builtin_bit_cast(short, b);
}

// ---------------- K_prep: LDS-tiled transpose, fp32[K][N] -> bf16[N][KP] ----------------
__global__ __launch_bounds__(256) void k_prep(
    const float* __restrict__ w1a, const float* __restrict__ w1b, const float* __restrict__ w1c,
    const float* __restrict__ w2a, const float* __restrict__ w2b, const float* __restrict__ w2c,
    const float* __restrict__ g1w, const float* __restrict__ g2w, const float* __restrict__ g3w,
    short* __restrict__ wt1a, short* __restrict__ wt1b, short* __restrict__ wt1c,
    short* __restrict__ wt2a, short* __restrict__ wt2b, short* __restrict__ wt2c,
    short* __restrict__ gt1,  short* __restrict__ gt2,  short* __restrict__ gt3) {
  __shared__ float tile[32][33];
  int t = blockIdx.x;
  const float* src; short* dst; int K, N, KP, tilesN, base;
  if      (t < 2)   { src=w1a; dst=wt1a; K=3;   N=64;   KP=32;  tilesN=2;  base=0; }
  else if (t < 6)   { src=w1b; dst=wt1b; K=64;  N=64;   KP=64;  tilesN=2;  base=2; }
  else if (t < 14)  { src=w1c; dst=wt1c; K=64;  N=128;  KP=64;  tilesN=4;  base=6; }
  else if (t < 34)  { src=w2a; dst=wt2a; K=131; N=128;  KP=160; tilesN=4;  base=14; }
  else if (t < 50)  { src=w2b; dst=wt2b; K=128; N=128;  KP=128; tilesN=4;  base=34; }
  else if (t < 82)  { src=w2c; dst=wt2c; K=128; N=256;  KP=128; tilesN=8;  base=50; }
  else if (t < 154) { src=g1w; dst=gt1;  K=259; N=256;  KP=288; tilesN=8;  base=82; }
  else if (t < 282) { src=g2w; dst=gt2;  K=256; N=512;  KP=256; tilesN=16; base=154; }
  else              { src=g3w; dst=gt3;  K=512; N=1024; KP=512; tilesN=32; base=282; }
  int idx = t - base;
  int tk = idx / tilesN, tn = idx - tk * tilesN;
  int k0 = tk * 32, n0 = tn * 32;
  int tx = threadIdx.x & 31, ty = threadIdx.x >> 5;
#pragma unroll
  for (int i = 0; i < 4; i++) {
    int k = k0 + ty + i * 8;
    tile[ty + i * 8][tx] = (k < K) ? src[k * N + n0 + tx] : 0.f;
  }
  __syncthreads();
#pragma unroll
  for (int i = 0; i < 4; i++) {
    int n = n0 + ty + i * 8;
    dst[n * KP + k0 + tx] = f2bs(tile[tx][ty + i * 8]);
  }
}

// ---------------- K0: gather pos1/pos2 + xg pos columns & pad ----------------
__global__ __launch_bounds__(256) void k_gather(const float* __restrict__ pos,
                                                const int* __restrict__ idx1,
                                                const int* __restrict__ idx2,
                                                float* __restrict__ pos1,
                                                float* __restrict__ pos2,
                                                short* __restrict__ xg) {
  int i = blockIdx.x * 256 + threadIdx.x;
  if (i < N1) {
    int s = idx1[i];
    pos1[i*3+0] = pos[s*3+0]; pos1[i*3+1] = pos[s*3+1]; pos1[i*3+2] = pos[s*3+2];
  } else if (i < N1 + N2) {
    int j = i - N1;
    int s = idx1[idx2[j]];
    float p0 = pos[s*3+0], p1 = pos[s*3+1], p2 = pos[s*3+2];
    pos2[j*3+0] = p0; pos2[j*3+1] = p1; pos2[j*3+2] = p2;
    short* row = xg + j * 288;
    row[256] = f2bs(p0); row[257] = f2bs(p1); row[258] = f2bs(p2);
#pragma unroll
    for (int c = 259; c < 288; c++) row[c] = 0;
  }
}

// ---------------- K1: conv1 MFMA, 2 segments/block (M=128) ----------------
// 4 waves split N; 8 m-tiles (rows 0..63 = seg0, 64..127 = seg1).
__global__ __launch_bounds__(256) void k_conv1(
    const float* __restrict__ pos, const float* __restrict__ pos1,
    const int* __restrict__ esrc,
    const short* __restrict__ wt1a, const float* __restrict__ b1a,
    const short* __restrict__ wt1b, const float* __restrict__ b1b,
    const short* __restrict__ wt1c, const float* __restrict__ b1c,
    short* __restrict__ x1b) {
  __shared__ __align__(16) short sA[128 * 40];
  __shared__ __align__(16) short sB[128 * 72];
  __shared__ __align__(16) short sC[128 * 72];
  __shared__ short sval[128];

  int seg0 = blockIdx.x * 2, tid = threadIdx.x;
  int lane = tid & 63;
  int w  = tid >> 6;
  int lr = lane & 15;
  int lg = lane >> 4;

  if (tid < 128) {
    int el = tid & 63, sg = tid >> 6;
    int seg = seg0 + sg;
    int e = seg * 64 + el;
    int s = esrc[e];
    sval[tid] = (short)((el == 0) || (s > esrc[e - 1]));
    short* row = sA + tid * 40;
    row[0] = f2bs(pos[s*3+0] - pos1[seg*3+0]);
    row[1] = f2bs(pos[s*3+1] - pos1[seg*3+1]);
    row[2] = f2bs(pos[s*3+2] - pos1[seg*3+2]);
#pragma unroll
    for (int i = 3; i < 40; i++) row[i] = 0;
  }
  __syncthreads();

  // layer A: K=32, wave w -> ch [w*16,+16)
  {
    f32x4 acc[8];
#pragma unroll
    for (int mt = 0; mt < 8; mt++) acc[mt] = (f32x4){0.f, 0.f, 0.f, 0.f};
    bf16x8 bf = *(const bf16x8*)(wt1a + (w*16 + lr) * 32 + lg * 8);
#pragma unroll
    for (int mt = 0; mt < 8; mt++) {
      bf16x8 af = *(const bf16x8*)(sA + (mt*16 + lr) * 40 + lg * 8);
      acc[mt] = __builtin_amdgcn_mfma_f32_16x16x32_bf16(af, bf, acc[mt], 0, 0, 0);
    }
    float bias = b1a[w*16 + lr];
#pragma unroll
    for (int mt = 0; mt < 8; mt++)
#pragma unroll
      for (int r = 0; r < 4; r++)
        sB[(mt*16 + lg*4 + r) * 72 + w*16 + lr] = f2bs(fmaxf(acc[mt][r] + bias, 0.f));
  }
  __syncthreads();

  // layer B: K=64
  {
    f32x4 acc[8];
#pragma unroll
    for (int mt = 0; mt < 8; mt++) acc[mt] = (f32x4){0.f, 0.f, 0.f, 0.f};
#pragma unroll
    for (int ks = 0; ks < 2; ks++) {
      bf16x8 bf = *(const bf16x8*)(wt1b + (w*16 + lr) * 64 + ks*32 + lg * 8);
#pragma unroll
      for (int mt = 0; mt < 8; mt++) {
        bf16x8 af = *(const bf16x8*)(sB + (mt*16 + lr) * 72 + ks*32 + lg * 8);
        acc[mt] = __builtin_amdgcn_mfma_f32_16x16x32_bf16(af, bf, acc[mt], 0, 0, 0);
      }
    }
    float bias = b1b[w*16 + lr];
#pragma unroll
    for (int mt = 0; mt < 8; mt++)
#pragma unroll
      for (int r = 0; r < 4; r++)
        sC[(mt*16 + lg*4 + r) * 72 + w*16 + lr] = f2bs(fmaxf(acc[mt][r] + bias, 0.f));
  }
  __syncthreads();

  // layer C: K=64, N=128 (wave: ch [w*32,+32), 2 ntiles), per-segment segmax
  {
    f32x4 acc[8][2];
#pragma unroll
    for (int mt = 0; mt < 8; mt++) {
      f32x4 vi;
#pragma unroll
      for (int r = 0; r < 4; r++) vi[r] = sval[mt*16 + lg*4 + r] ? 0.f : -1e30f;
      acc[mt][0] = vi; acc[mt][1] = vi;
    }
#pragma unroll
    for (int ks = 0; ks < 2; ks++) {
      bf16x8 bf0 = *(const bf16x8*)(wt1c + (w*32 + lr)      * 64 + ks*32 + lg * 8);
      bf16x8 bf1 = *(const bf16x8*)(wt1c + (w*32 + 16 + lr) * 64 + ks*32 + lg * 8);
#pragma unroll
      for (int mt = 0; mt < 8; mt++) {
        bf16x8 af = *(const bf16x8*)(sC + (mt*16 + lr) * 72 + ks*32 + lg * 8);
        acc[mt][0] = __builtin_amdgcn_mfma_f32_16x16x32_bf16(af, bf0, acc[mt][0], 0, 0, 0);
        acc[mt][1] = __builtin_amdgcn_mfma_f32_16x16x32_bf16(af, bf1, acc[mt][1], 0, 0, 0);
      }
    }
#pragma unroll
    for (int nt = 0; nt < 2; nt++) {
#pragma unroll
      for (int sg = 0; sg < 2; sg++) {
        float m = -3e38f;
#pragma unroll
        for (int mt = 0; mt < 4; mt++)
#pragma unroll
          for (int r = 0; r < 4; r++) m = fmaxf(m, acc[sg*4 + mt][nt][r]);
        m = fmaxf(m, __shfl_xor(m, 16, 64));
        m = fmaxf(m, __shfl_xor(m, 32, 64));
        if (lg == 0) {
          int ch = w*32 + nt*16 + lr;
          x1b[(seg0 + sg)*128 + ch] = f2bs(fmaxf(m + b1c[ch], 0.f));
        }
      }
    }
  }
}

// ---------------- K2: conv2 MFMA, 2 segments/block (M=128) ----------------
__global__ __launch_bounds__(256) void k_conv2(
    const float* __restrict__ pos1, const float* __restrict__ pos2,
    const int* __restrict__ esrc, const short* __restrict__ x1b,
    const short* __restrict__ wt2a, const float* __restrict__ b2a,
    const short* __restrict__ wt2b, const float* __restrict__ b2b,
    const short* __restrict__ wt2c, const float* __restrict__ b2c,
    short* __restrict__ xg) {
  __shared__ __align__(16) short sX[128 * 168];
  __shared__ __align__(16) short sY[128 * 136];
  __shared__ short sval[128];

  int seg0 = blockIdx.x * 2, tid = threadIdx.x;
  int lane = tid & 63;
  int w  = tid >> 6;
  int lr = lane & 15;
  int lg = lane >> 4;

  // stage feat rows: 2 threads per row, 8 uint4 each (64 shorts = half of the
  // 128-bf16 x1b row per thread).  BUG FIX (round-9/11 failure): loop was i<4,
  // leaving shorts 32..63 and 96..127 of every row as uninitialized LDS.
  {
    int r = tid >> 1, half = tid & 1;
    int sg = r >> 6, el = r & 63;
    int s = esrc[(seg0 + sg)*64 + el];
    const uint4* src = (const uint4*)(x1b + s * 128 + half * 64);
    uint4* dst = (uint4*)(sX + r * 168 + half * 64);
#pragma unroll
    for (int i = 0; i < 8; i++) dst[i] = src[i];
  }
  if (tid < 128) {
    int el = tid & 63, sg = tid >> 6;
    int seg = seg0 + sg;
    int e = seg * 64 + el;
    int s = esrc[e];
    sval[tid] = (short)((el == 0) || (s > esrc[e - 1]));
    short* row = sX + tid * 168;
    row[128] = f2bs(pos1[s*3+0] - pos2[seg*3+0]);
    row[129] = f2bs(pos1[s*3+1] - pos2[seg*3+1]);
    row[130] = f2bs(pos1[s*3+2] - pos2[seg*3+2]);
#pragma unroll
    for (int i = 131; i < 168; i++) row[i] = 0;
  }
  __syncthreads();

  // layer A: K=160, wave -> ch [w*32,+32), 2 ntiles
  {
    f32x4 acc[8][2];
#pragma unroll
    for (int mt = 0; mt < 8; mt++) { acc[mt][0] = (f32x4){0.f,0.f,0.f,0.f}; acc[mt][1] = (f32x4){0.f,0.f,0.f,0.f}; }
#pragma unroll
    for (int ks = 0; ks < 5; ks++) {
      bf16x8 bf0 = *(const bf16x8*)(wt2a + (w*32 + lr)      * 160 + ks*32 + lg * 8);
      bf16x8 bf1 = *(const bf16x8*)(wt2a + (w*32 + 16 + lr) * 160 + ks*32 + lg * 8);
#pragma unroll
      for (int mt = 0; mt < 8; mt++) {
        bf16x8 af = *(const bf16x8*)(sX + (mt*16 + lr) * 168 + ks*32 + lg * 8);
        acc[mt][0] = __builtin_amdgcn_mfma_f32_16x16x32_bf16(af, bf0, acc[mt][0], 0, 0, 0);
        acc[mt][1] = __builtin_amdgcn_mfma_f32_16x16x32_bf16(af, bf1, acc[mt][1], 0, 0, 0);
      }
    }
    float bias0 = b2a[w*32 + lr], bias1 = b2a[w*32 + 16 + lr];
#pragma unroll
    for (int mt = 0; mt < 8; mt++)
#pragma unroll
      for (int r = 0; r < 4; r++) {
        int row = mt*16 + lg*4 + r;
        sY[row * 136 + w*32 + lr]      = f2bs(fmaxf(acc[mt][0][r] + bias0, 0.f));
        sY[row * 136 + w*32 + 16 + lr] = f2bs(fmaxf(acc[mt][1][r] + bias1, 0.f));
      }
  }
  __syncthreads();

  // layer B: K=128; read sY(136), write sX reused (stride 136)
  {
    f32x4 acc[8][2];
#pragma unroll
    for (int mt = 0; mt < 8; mt++) { acc[mt][0] = (f32x4){0.f,0.f,0.f,0.f}; acc[mt][1] = (f32x4){0.f,0.f,0.f,0.f}; }
#pragma unroll
    for (int ks = 0; ks < 4; ks++) {
      bf16x8 bf0 = *(const bf16x8*)(wt2b + (w*32 + lr)      * 128 + ks*32 + lg * 8);
      bf16x8 bf1 = *(const bf16x8*)(wt2b + (w*32 + 16 + lr) * 128 + ks*32 + lg * 8);
#pragma unroll
      for (int mt = 0; mt < 8; mt++) {
        bf16x8 af = *(const bf16x8*)(sY + (mt*16 + lr) * 136 + ks*32 + lg * 8);
        acc[mt][0] = __builtin_amdgcn_mfma_f32_16x16x32_bf16(af, bf0, acc[mt][0], 0, 0, 0);
        acc[mt][1] = __builtin_amdgcn_mfma_f32_16x16x32_bf16(af, bf1, acc[mt][1], 0, 0, 0);
      }
    }
    float bias0 = b2b[w*32 + lr], bias1 = b2b[w*32 + 16 + lr];
    __syncthreads();
#pragma unroll
    for (int mt = 0; mt < 8; mt++)
#pragma unroll
      for (int r = 0; r < 4; r++) {
        int row = mt*16 + lg*4 + r;
        sX[row * 136 + w*32 + lr]      = f2bs(fmaxf(acc[mt][0][r] + bias0, 0.f));
        sX[row * 136 + w*32 + 16 + lr] = f2bs(fmaxf(acc[mt][1][r] + bias1, 0.f));
      }
  }
  __syncthreads();

  // layer C: K=128, N=256 (wave: ch [w*64,+64), 4 ntiles in 2 passes), per-seg segmax
#pragma unroll
  for (int half = 0; half < 2; half++) {
    f32x4 acc[8][2];
#pragma unroll
    for (int mt = 0; mt < 8; mt++) {
      f32x4 vi;
#pragma unroll
      for (int r = 0; r < 4; r++) vi[r] = sval[mt*16 + lg*4 + r] ? 0.f : -1e30f;
      acc[mt][0] = vi; acc[mt][1] = vi;
    }
#pragma unroll
    for (int ks = 0; ks < 4; ks++) {
      bf16x8 bf0 = *(const bf16x8*)(wt2c + (w*64 + half*32 + lr)      * 128 + ks*32 + lg * 8);
      bf16x8 bf1 = *(const bf16x8*)(wt2c + (w*64 + half*32 + 16 + lr) * 128 + ks*32 + lg * 8);
#pragma unroll
      for (int mt = 0; mt < 8; mt++) {
        bf16x8 af = *(const bf16x8*)(sX + (mt*16 + lr) * 136 + ks*32 + lg * 8);
        acc[mt][0] = __builtin_amdgcn_mfma_f32_16x16x32_bf16(af, bf0, acc[mt][0], 0, 0, 0);
        acc[mt][1] = __builtin_amdgcn_mfma_f32_16x16x32_bf16(af, bf1, acc[mt][1], 0, 0, 0);
      }
    }
#pragma unroll
    for (int nt = 0; nt < 2; nt++) {
#pragma unroll
      for (int sg = 0; sg < 2; sg++) {
        float m = -3e38f;
#pragma unroll
        for (int mt = 0; mt < 4; mt++)
#pragma unroll
          for (int r = 0; r < 4; r++) m = fmaxf(m, acc[sg*4 + mt][nt][r]);
        m = fmaxf(m, __shfl_xor(m, 16, 64));
        m = fmaxf(m, __shfl_xor(m, 32, 64));
        if (lg == 0) {
          int ch = w*64 + half*32 + nt*16 + lr;
          xg[(seg0 + sg)*288 + ch] = f2bs(fmaxf(m + b2c[ch], 0.f));
        }
      }
    }
  }
}

// ---------------- K3: generic MFMA GEMM for the g-MLP chain (round-3/10 version) ----------
// Block tile: M=64 x N=256 (4 waves x 64ch); grid = 32 * (N/256), mb = bid&31.
template<int KP, bool RELU, bool POOL>
__global__ __launch_bounds__(256) void k_gemm(
    const short* __restrict__ A, const short* __restrict__ Bt,
    const float* __restrict__ bias, short* __restrict__ outB,
    float* __restrict__ outP, int N) {
  constexpr int CHUNK = (KP > 288) ? 256 : KP;
  constexpr int NCH   = KP / CHUNK;
  constexpr int LS    = CHUNK + 8;
  constexpr int CQ    = CHUNK / 4;
  __shared__ __align__(16) short sA[64 * LS];

  int bid = blockIdx.x;
  int mb = bid & 31, nb = bid >> 5;
  int tid = threadIdx.x;
  int lane = tid & 63, w = tid >> 6;
  int lr = lane & 15, lg = lane >> 4;
  int n0 = nb * 256 + w * 64;

  f32x4 acc[4][4];
#pragma unroll
  for (int mt = 0; mt < 4; mt++)
#pragma unroll
    for (int nt = 0; nt < 4; nt++) acc[mt][nt] = (f32x4){0.f, 0.f, 0.f, 0.f};

#pragma unroll
  for (int kc = 0; kc < NCH; kc++) {
    if (kc) __syncthreads();
    {
      int r = tid >> 2, q = tid & 3;
      const uint4* src = (const uint4*)(A + (mb*64 + r) * KP + kc*CHUNK + q*CQ);
      uint4* dst = (uint4*)(sA + r * LS + q * CQ);
#pragma unroll
      for (int i = 0; i < CQ/8; i++) dst[i] = src[i];
    }
    __syncthreads();
#pragma unroll
    for (int ks = 0; ks < CHUNK/32; ks++) {
      bf16x8 bf[4];
#pragma unroll
      for (int nt = 0; nt < 4; nt++)
        bf[nt] = *(const bf16x8*)(Bt + (n0 + nt*16 + lr) * KP + kc*CHUNK + ks*32 + lg*8);
#pragma unroll
      for (int mt = 0; mt < 4; mt++) {
        bf16x8 af = *(const bf16x8*)(sA + (mt*16 + lr) * LS + ks*32 + lg*8);
#pragma unroll
        for (int nt = 0; nt < 4; nt++)
          acc[mt][nt] = __builtin_amdgcn_mfma_f32_16x16x32_bf16(af, bf[nt], acc[mt][nt], 0, 0, 0);
      }
    }
  }

  if constexpr (POOL) {
#pragma unroll
    for (int nt = 0; nt < 4; nt++) {
      float m = -3e38f;
#pragma unroll
      for (int mt = 0; mt < 4; mt++)
#pragma unroll
        for (int rr = 0; rr < 4; rr++) m = fmaxf(m, acc[mt][nt][rr]);
      m = fmaxf(m, __shfl_xor(m, 16, 64));
      m = fmaxf(m, __shfl_xor(m, 32, 64));
      if (lg == 0) {
        int col = n0 + nt*16 + lr;
        outP[mb * 1024 + col] = m + bias[col];
      }
    }
  } else {
#pragma unroll
    for (int nt = 0; nt < 4; nt++) {
      int col = n0 + nt*16 + lr;
      float bv = bias[col];
#pragma unroll
      for (int mt = 0; mt < 4; mt++)
#pragma unroll
        for (int rr = 0; rr < 4; rr++) {
          int row = mb*64 + mt*16 + lg*4 + rr;
          float v = acc[mt][nt][rr] + bv;
          if (RELU) v = fmaxf(v, 0.f);
          outB[row * N + col] = f2bs(v);
        }
    }
  }
}

// ---------------- K4: reduce 2 partials per batch -> g[16][1024] ----------------
__global__ __launch_bounds__(256) void k_pool(const float* __restrict__ gpart,
                                              float* __restrict__ g) {
  int gid = blockIdx.x * 256 + threadIdx.x;  // 16384
  int b = gid >> 10, ch = gid & 1023;
  g[gid] = fmaxf(gpart[(b*2) * 1024 + ch], gpart[(b*2 + 1) * 1024 + ch]);
}

// ---------------- head layers ----------------
__global__ __launch_bounds__(256) void k_l1(const float* __restrict__ g,
                                            const float* __restrict__ w,
                                            const float* __restrict__ bias,
                                            float* __restrict__ out) {
  int gid = blockIdx.x * 256 + threadIdx.x;  // 8192
  int b = gid >> 9, j = gid & 511;
  const float* gr = g + b * 1024;
  float acc = bias[j];
  for (int k = 0; k < 1024; k++) acc += gr[k] * w[k * 512 + j];
  out[gid] = fmaxf(acc, 0.f);
}

__global__ __launch_bounds__(256) void k_l2(const float* __restrict__ h,
                                            const float* __restrict__ w,
                                            const float* __restrict__ bias,
                                            float* __restrict__ out) {
  int gid = blockIdx.x * 256 + threadIdx.x;  // 4096
  int b = gid >> 8, j = gid & 255;
  const float* hr = h + b * 512;
  float acc = bias[j];
  for (int k = 0; k < 512; k++) acc += hr[k] * w[k * 256 + j];
  out[gid] = fmaxf(acc, 0.f);
}

__global__ __launch_bounds__(256) void k_l3(const float* __restrict__ h,
                                            const float* __restrict__ w,
                                            const float* __restrict__ bias,
                                            float* __restrict__ out) {
  __shared__ float sl[160];
  int tid = threadIdx.x;
  if (tid < 160) {
    int b = tid / 10, j = tid - b * 10;
    const float* hr = h + b * 256;
    float acc = bias[j];
    for (int k = 0; k < 256; k++) acc += hr[k] * w[k * 10 + j];
    sl[tid] = acc;
  }
  __syncthreads();
  if (tid < 16) {
    float m = -INFINITY;
#pragma unroll
    for (int j = 0; j < 10; j++) m = fmaxf(m, sl[tid * 10 + j]);
    float s = 0.f;
#pragma unroll
    for (int j = 0; j < 10; j++) s += expf(sl[tid * 10 + j] - m);
    float lse = m + logf(s);
#pragma unroll
    for (int j = 0; j < 10; j++) out[tid * 10 + j] = sl[tid * 10 + j] - lse;
  }
}

extern "C" void kernel_launch(void* const* d_in, const int* in_sizes, int n_in,
                              void* d_out, int out_size, void* d_ws, size_t ws_size,
                              hipStream_t stream) {
  (void)in_sizes; (void)n_in; (void)out_size; (void)ws_size;
  const float* pos    = (const float*)d_in[0];
  const int*   idx1   = (const int*)d_in[1];
  const int*   e1_src = (const int*)d_in[2];
  const int*   idx2   = (const int*)d_in[5];
  const int*   e2_src = (const int*)d_in[6];
  const float* w1a = (const float*)d_in[9],  *b1a = (const float*)d_in[10];
  const float* w1b = (const float*)d_in[11], *b1b = (const float*)d_in[12];
  const float* w1c = (const float*)d_in[13], *b1c = (const float*)d_in[14];
  const float* w2a = (const float*)d_in[15], *b2a = (const float*)d_in[16];
  const float* w2b = (const float*)d_in[17], *b2b = (const float*)d_in[18];
  const float* w2c = (const float*)d_in[19], *b2c = (const float*)d_in[20];
  const float* g1w = (const float*)d_in[21], *g1b = (const float*)d_in[22];
  const float* g2w = (const float*)d_in[23], *g2b = (const float*)d_in[24];
  const float* g3w = (const float*)d_in[25], *g3b = (const float*)d_in[26];
  const float* l1w = (const float*)d_in[27], *l1b = (const float*)d_in[28];
  const float* l2w = (const float*)d_in[29], *l2b = (const float*)d_in[30];
  const float* l3w = (const float*)d_in[31], *l3b = (const float*)d_in[32];

  float* ws    = (float*)d_ws;
  float* pos1  = ws + POS1_OFF;
  float* pos2  = ws + POS2_OFF;
  float* gpart = ws + GPART_OFF;
  float* g     = ws + G_OFF;
  float* h1h   = ws + H1H_OFF;
  float* h2h   = ws + H2H_OFF;
  short* sbase = (short*)(ws + FLT_END);
  short* x1b   = sbase + X1B_OFF;
  short* xg    = sbase + XG_OFF;
  short* h1    = sbase + H1_OFF;
  short* h2    = sbase + H2_OFF;
  short* wt1a  = sbase + WT1A_OFF;
  short* wt1b  = sbase + WT1B_OFF;
  short* wt1c  = sbase + WT1C_OFF;
  short* wt2a  = sbase + WT2A_OFF;
  short* wt2b  = sbase + WT2B_OFF;
  short* wt2c  = sbase + WT2C_OFF;
  short* gt1   = sbase + GT1_OFF;
  short* gt2   = sbase + GT2_OFF;
  short* gt3   = sbase + GT3_OFF;

  k_prep<<<794, 256, 0, stream>>>(w1a, w1b, w1c, w2a, w2b, w2c, g1w, g2w, g3w,
                                  wt1a, wt1b, wt1c, wt2a, wt2b, wt2c, gt1, gt2, gt3);
  k_gather<<<(N1 + N2 + 255) / 256, 256, 0, stream>>>(pos, idx1, idx2, pos1, pos2, xg);
  k_conv1<<<N1/2, 256, 0, stream>>>(pos, pos1, e1_src, wt1a, b1a, wt1b, b1b, wt1c, b1c, x1b);
  k_conv2<<<N2/2, 256, 0, stream>>>(pos1, pos2, e2_src, x1b, wt2a, b2a, wt2b, b2b, wt2c, b2c, xg);
  k_gemm<288, true,  false><<<32,  256, 0, stream>>>(xg, gt1, g1b, h1, nullptr, 256);
  k_gemm<256, true,  false><<<64,  256, 0, stream>>>(h1, gt2, g2b, h2, nullptr, 512);
  k_gemm<512, false, true ><<<128, 256, 0, stream>>>(h2, gt3, g3b, nullptr, gpart, 1024);
  k_pool<<<64, 256, 0, stream>>>(gpart, g);
  k_l1<<<32, 256, 0, stream>>>(g, l1w, l1b, h1h);
  k_l2<<<16, 256, 0, stream>>>(h1h, l2w, l2b, h2h);
  k_l3<<<1, 256, 0, stream>>>(h2h, l3w, l3b, (float*)d_out);
}